// Round 4
// baseline (3051.268 us; speedup 1.0000x reference)
//
#include <hip/hip_runtime.h>
#include <hip/hip_bf16.h>

typedef unsigned short u16;
typedef float f32x4 __attribute__((ext_vector_type(4)));
typedef short s16x8 __attribute__((ext_vector_type(8)));
typedef unsigned short u16x4 __attribute__((ext_vector_type(4)));

#define T_TOK 4096
#define DM 1024
#define NQKV 3072
#define LN_EPS 1e-6f
#define KDIM 1024
#define NT 32  // KDIM / 32 k-tiles

// ---- async global->LDS, 16B per lane. LDS dest = uniform base + lane*16. ----
__device__ __forceinline__ void gll16(const void* g, void* l) {
    __builtin_amdgcn_global_load_lds(
        (const __attribute__((address_space(1))) void*)g,
        (__attribute__((address_space(3))) void*)l, 16, 0, 0);
}

// ---- XCD-aware block swizzle (requires gx*gy % 8 == 0; all our grids comply) ----
__device__ __forceinline__ void xcd_swz(int& bx, int& by) {
    const int gx = gridDim.x, gy = gridDim.y;
    const int nwg = gx * gy;
    const int lin = by * gx + bx;
    const int cpx = nwg >> 3;
    const int swz = (lin & 7) * cpx + (lin >> 3);
    bx = swz % gx;
    by = swz / gx;
}

// ---- bf16 split: x ~= hi + lo, each RNE bf16. |err| <= ~2^-17 |x| ----
__device__ __forceinline__ void bf16_split(float x, u16& hi, u16& lo) {
    unsigned xb = __float_as_uint(x);
    unsigned rh = xb + 0x7fffu + ((xb >> 16) & 1u);
    hi = (u16)(rh >> 16);
    float hf = __uint_as_float(((unsigned)hi) << 16);
    float rs = x - hf;
    unsigned rb = __float_as_uint(rs);
    unsigned rl = rb + 0x7fffu + ((rb >> 16) & 1u);
    lo = (u16)(rl >> 16);
}
__device__ __forceinline__ float bf16_comb(u16 h, u16 l) {
    return __uint_as_float(((unsigned)h) << 16) + __uint_as_float(((unsigned)l) << 16);
}

// 3-pass split MFMA: acc += ah*bh + ah*bl + al*bh
#define MFMA3(ACC, AH, AL, BH, BL) { \
    ACC = __builtin_amdgcn_mfma_f32_16x16x32_bf16(AH, BH, ACC, 0, 0, 0); \
    ACC = __builtin_amdgcn_mfma_f32_16x16x32_bf16(AH, BL, ACC, 0, 0, 0); \
    ACC = __builtin_amdgcn_mfma_f32_16x16x32_bf16(AL, BH, ACC, 0, 0, 0); }

// ---- weight transpose + split: src [K][N] f32 (batch z) -> dh/dl [N][K] bf16 ----
__global__ __launch_bounds__(256)
void convert_w(const float* __restrict__ src, u16* __restrict__ dh,
               u16* __restrict__ dl, int K, int N) {
    const int e = blockIdx.z;
    src += (size_t)e * K * N;
    dh  += (size_t)e * K * N;
    dl  += (size_t)e * K * N;
    __shared__ float ts[64][65];
    const int t = threadIdx.x;
    const int k0 = blockIdx.y * 64, n0 = blockIdx.x * 64;
    const int r = t >> 4, c4 = (t & 15) * 4;
    #pragma unroll
    for (int i = 0; i < 4; ++i) {
        const int kr = r + i * 16;
        float4 v = *(const float4*)(src + (size_t)(k0 + kr) * N + n0 + c4);
        ts[kr][c4 + 0] = v.x; ts[kr][c4 + 1] = v.y;
        ts[kr][c4 + 2] = v.z; ts[kr][c4 + 3] = v.w;
    }
    __syncthreads();
    #pragma unroll
    for (int i = 0; i < 4; ++i) {
        const int nr = r + i * 16;
        u16x4 h4, l4;
        #pragma unroll
        for (int j = 0; j < 4; ++j) {
            u16 h, l; bf16_split(ts[c4 + j][nr], h, l);
            h4[j] = h; l4[j] = l;
        }
        *(u16x4*)(dh + (size_t)(n0 + nr) * K + k0 + c4) = h4;
        *(u16x4*)(dl + (size_t)(n0 + nr) * K + k0 + c4) = l4;
    }
}

// ---- LayerNorm -> bf16 hi/lo planes ----
__global__ __launch_bounds__(256)
void ln_kernel(const float* __restrict__ x, const float* __restrict__ sc,
               const float* __restrict__ bi, u16* __restrict__ yh,
               u16* __restrict__ yl) {
    const int row = blockIdx.x;
    const int t = threadIdx.x;
    const float* xr = x + (size_t)row * DM;
    float4 v = *(const float4*)(xr + t * 4);
    float s  = v.x + v.y + v.z + v.w;
    float s2 = v.x*v.x + v.y*v.y + v.z*v.z + v.w*v.w;
    #pragma unroll
    for (int off = 32; off; off >>= 1) {
        s  += __shfl_down(s, off);
        s2 += __shfl_down(s2, off);
    }
    __shared__ float ss[4], ss2[4];
    const int wid = t >> 6;
    if ((t & 63) == 0) { ss[wid] = s; ss2[wid] = s2; }
    __syncthreads();
    const float tot  = ss[0] + ss[1] + ss[2] + ss[3];
    const float tot2 = ss2[0] + ss2[1] + ss2[2] + ss2[3];
    const float mu  = tot * (1.0f / DM);
    const float var = tot2 * (1.0f / DM) - mu * mu;
    const float rcp = rsqrtf(var + LN_EPS);
    float4 sv = *(const float4*)(sc + t * 4);
    float4 bv = *(const float4*)(bi + t * 4);
    float o[4];
    o[0] = (v.x - mu) * rcp * sv.x + bv.x;
    o[1] = (v.y - mu) * rcp * sv.y + bv.y;
    o[2] = (v.z - mu) * rcp * sv.z + bv.z;
    o[3] = (v.w - mu) * rcp * sv.w + bv.w;
    u16x4 h4, l4;
    #pragma unroll
    for (int j = 0; j < 4; ++j) { u16 h, l; bf16_split(o[j], h, l); h4[j] = h; l4[j] = l; }
    *(u16x4*)(yh + (size_t)row * DM + t * 4) = h4;
    *(u16x4*)(yl + (size_t)row * DM + t * 4) = l4;
}

// ---- MFMA GEMM 128x128x32, gll staging. A [M][K] planes, B [N][K] planes ----
// MODE 0: C = A@B^T + bias ; MODE 1: C = A@B^T + bias + res
template<int MODE>
__global__ __launch_bounds__(256, 2)
void gemm_mfma(const u16* __restrict__ Ah, const u16* __restrict__ Al,
               const u16* __restrict__ Bh, const u16* __restrict__ Bl,
               const float* __restrict__ bias, const float* __restrict__ res,
               float* __restrict__ C, int N) {
    __shared__ __align__(16) u16 Ahs[128 * 32], Als[128 * 32];
    __shared__ __align__(16) u16 Bhs[128 * 32], Bls[128 * 32];
    int bx = blockIdx.x, by = blockIdx.y;
    xcd_swz(bx, by);
    const int t = threadIdx.x;
    const int m0 = by * 128, n0 = bx * 128;
    const int lane = t & 63, wid = t >> 6;
    const int wm = wid >> 1, wn = wid & 1;
    const int lr = lane & 15, lc = lane >> 4;
    // gll mapping: lane -> row lane/4 (of 16-row chunk), k = (lane%4)*8
    const int srow = lane >> 2, skk = (lane & 3) * 8;
    const int w32 = wid * 32;
    const u16* Agh = Ah + (size_t)(m0 + w32 + srow) * KDIM + skk;
    const u16* Agl = Al + (size_t)(m0 + w32 + srow) * KDIM + skk;
    const u16* Bgh = Bh + (size_t)(n0 + w32 + srow) * KDIM + skk;
    const u16* Bgl = Bl + (size_t)(n0 + w32 + srow) * KDIM + skk;

    f32x4 acc[4][4];
    #pragma unroll
    for (int i = 0; i < 4; ++i)
        #pragma unroll
        for (int j = 0; j < 4; ++j)
            #pragma unroll
            for (int r = 0; r < 4; ++r) acc[i][j][r] = 0.0f;

    for (int kt = 0; kt < NT; ++kt) {
        const int ko = kt * 32;
        gll16(Agh + ko,              &Ahs[w32 * 32]);
        gll16(Agh + ko + 16 * KDIM,  &Ahs[(w32 + 16) * 32]);
        gll16(Agl + ko,              &Als[w32 * 32]);
        gll16(Agl + ko + 16 * KDIM,  &Als[(w32 + 16) * 32]);
        gll16(Bgh + ko,              &Bhs[w32 * 32]);
        gll16(Bgh + ko + 16 * KDIM,  &Bhs[(w32 + 16) * 32]);
        gll16(Bgl + ko,              &Bls[w32 * 32]);
        gll16(Bgl + ko + 16 * KDIM,  &Bls[(w32 + 16) * 32]);
        __syncthreads();  // compiler emits vmcnt(0) drain before barrier
        s16x8 fa_h[4], fa_l[4], fb_h[4], fb_l[4];
        #pragma unroll
        for (int fi = 0; fi < 4; ++fi) {
            const int ro = (wm * 64 + fi * 16 + lr) * 32 + lc * 8;
            fa_h[fi] = *(const s16x8*)&Ahs[ro];
            fa_l[fi] = *(const s16x8*)&Als[ro];
        }
        #pragma unroll
        for (int fj = 0; fj < 4; ++fj) {
            const int ro = (wn * 64 + fj * 16 + lr) * 32 + lc * 8;
            fb_h[fj] = *(const s16x8*)&Bhs[ro];
            fb_l[fj] = *(const s16x8*)&Bls[ro];
        }
        #pragma unroll
        for (int fi = 0; fi < 4; ++fi)
            #pragma unroll
            for (int fj = 0; fj < 4; ++fj)
                MFMA3(acc[fi][fj], fa_h[fi], fa_l[fi], fb_h[fj], fb_l[fj])
        __syncthreads();  // protect LDS before next stage
    }

    #pragma unroll
    for (int fj = 0; fj < 4; ++fj) {
        const int col = n0 + wn * 64 + fj * 16 + lr;
        const float bv = bias[col];
        #pragma unroll
        for (int fi = 0; fi < 4; ++fi)
            #pragma unroll
            for (int r = 0; r < 4; ++r) {
                const int row = m0 + wm * 64 + fi * 16 + lc * 4 + r;
                float v = acc[fi][fj][r] + bv;
                if (MODE == 1) v += res[(size_t)row * N + col];
                C[(size_t)row * N + col] = v;
            }
    }
}

// ---- MoE GEMM 128x64x32: comb = sum_e r[:,e]*(y@We[e]^T + be[e]) -> planes ----
__global__ __launch_bounds__(256, 2)
void moe_gemm(const u16* __restrict__ Ah, const u16* __restrict__ Al,
              const u16* __restrict__ Bh, const u16* __restrict__ Bl,
              const float* __restrict__ be, const float* __restrict__ gate,
              u16* __restrict__ Ch, u16* __restrict__ Cl) {
    __shared__ __align__(16) u16 Ahs[128 * 32], Als[128 * 32];
    __shared__ __align__(16) u16 Bhs[64 * 32],  Bls[64 * 32];
    int bx = blockIdx.x, by = blockIdx.y;
    xcd_swz(bx, by);
    const int t = threadIdx.x;
    const int m0 = by * 128, n0 = bx * 64;
    const int lane = t & 63, wid = t >> 6;
    const int wm = wid >> 1, wn = wid & 1;
    const int lr = lane & 15, lc = lane >> 4;
    const int srow = lane >> 2, skk = (lane & 3) * 8;
    const int w32 = wid * 32, w16 = wid * 16;
    const u16* Agh = Ah + (size_t)(m0 + w32 + srow) * KDIM + skk;
    const u16* Agl = Al + (size_t)(m0 + w32 + srow) * KDIM + skk;

    f32x4 out[4][2];
    #pragma unroll
    for (int i = 0; i < 4; ++i)
        #pragma unroll
        for (int j = 0; j < 2; ++j)
            #pragma unroll
            for (int r = 0; r < 4; ++r) out[i][j][r] = 0.0f;

    for (int e = 0; e < 8; ++e) {
        const u16* Bgh = Bh + ((size_t)e << 20) + (size_t)(n0 + w16 + srow) * KDIM + skk;
        const u16* Bgl = Bl + ((size_t)e << 20) + (size_t)(n0 + w16 + srow) * KDIM + skk;
        f32x4 acc[4][2];
        #pragma unroll
        for (int i = 0; i < 4; ++i)
            #pragma unroll
            for (int j = 0; j < 2; ++j)
                #pragma unroll
                for (int r = 0; r < 4; ++r) acc[i][j][r] = 0.0f;

        for (int kt = 0; kt < NT; ++kt) {
            const int ko = kt * 32;
            gll16(Agh + ko,             &Ahs[w32 * 32]);
            gll16(Agh + ko + 16 * KDIM, &Ahs[(w32 + 16) * 32]);
            gll16(Agl + ko,             &Als[w32 * 32]);
            gll16(Agl + ko + 16 * KDIM, &Als[(w32 + 16) * 32]);
            gll16(Bgh + ko,             &Bhs[w16 * 32]);
            gll16(Bgl + ko,             &Bls[w16 * 32]);
            __syncthreads();
            s16x8 fa_h[4], fa_l[4], fb_h[2], fb_l[2];
            #pragma unroll
            for (int fi = 0; fi < 4; ++fi) {
                const int ro = (wm * 64 + fi * 16 + lr) * 32 + lc * 8;
                fa_h[fi] = *(const s16x8*)&Ahs[ro];
                fa_l[fi] = *(const s16x8*)&Als[ro];
            }
            #pragma unroll
            for (int fj = 0; fj < 2; ++fj) {
                const int ro = (wn * 32 + fj * 16 + lr) * 32 + lc * 8;
                fb_h[fj] = *(const s16x8*)&Bhs[ro];
                fb_l[fj] = *(const s16x8*)&Bls[ro];
            }
            #pragma unroll
            for (int fi = 0; fi < 4; ++fi)
                #pragma unroll
                for (int fj = 0; fj < 2; ++fj)
                    MFMA3(acc[fi][fj], fa_h[fi], fa_l[fi], fb_h[fj], fb_l[fj])
            __syncthreads();
        }
        float bv[2];
        #pragma unroll
        for (int fj = 0; fj < 2; ++fj)
            bv[fj] = be[e * 1024 + n0 + wn * 32 + fj * 16 + lr];
        #pragma unroll
        for (int fi = 0; fi < 4; ++fi)
            #pragma unroll
            for (int r = 0; r < 4; ++r) {
                const int row = m0 + wm * 64 + fi * 16 + lc * 4 + r;
                const float g = gate[(size_t)row * 8 + e];
                #pragma unroll
                for (int fj = 0; fj < 2; ++fj)
                    out[fi][fj][r] += g * (acc[fi][fj][r] + bv[fj]);
            }
    }
    #pragma unroll
    for (int fi = 0; fi < 4; ++fi)
        #pragma unroll
        for (int fj = 0; fj < 2; ++fj) {
            const int col = n0 + wn * 32 + fj * 16 + lr;
            #pragma unroll
            for (int r = 0; r < 4; ++r) {
                const int row = m0 + wm * 64 + fi * 16 + lc * 4 + r;
                u16 h, l; bf16_split(out[fi][fj][r], h, l);
                Ch[(size_t)row * 1024 + col] = h;
                Cl[(size_t)row * 1024 + col] = l;
            }
        }
}

// ---- flash attention (fp32 VALU), 2 waves/block sharing K/V LDS tiles ----
// wave0 stages K, wave1 stages V; each wave owns 64 q-rows.
__global__ __launch_bounds__(128, 2)
void attn_kernel(const float* __restrict__ qkv, u16* __restrict__ oh,
                 u16* __restrict__ ol) {
    const int t = threadIdx.x;
    const int lane = t & 63, wid = t >> 6;
    const int q0 = blockIdx.x * 128 + wid * 64;
    const int bh = blockIdx.y;
    const int b = bh >> 4, h = bh & 15;
    __shared__ __align__(16) float ks[64][64];
    __shared__ __align__(16) float vs[64][64];
    const size_t RS = NQKV;
    const float* qrow = qkv + (size_t)(b * 2048 + q0 + lane) * RS + h * 64;
    float q[64];
    #pragma unroll
    for (int i = 0; i < 16; ++i) {
        float4 v4 = *(const float4*)(qrow + i * 4);
        q[4*i] = v4.x; q[4*i+1] = v4.y; q[4*i+2] = v4.z; q[4*i+3] = v4.w;
    }
    float oa[64];
    #pragma unroll
    for (int d = 0; d < 64; ++d) oa[d] = 0.0f;
    float mrun = -3.0e38f, l = 0.0f;
    const float scale = 0.125f;
    const int srow = lane >> 4;          // 0..3
    const int scol = (lane & 15) * 4;    // f32 col

    for (int kt = 0; kt < 32; ++kt) {
        __syncthreads();  // prior tile fully consumed by both waves
        const float* kbase = qkv + (size_t)(b * 2048 + kt * 64) * RS + 1024 + h * 64;
        const float* vbase = kbase + 1024;
        if (wid == 0) {
            #pragma unroll
            for (int i = 0; i < 16; ++i)
                gll16(kbase + (size_t)(i * 4 + srow) * RS + scol, &ks[i * 4][0]);
        } else {
            #pragma unroll
            for (int i = 0; i < 16; ++i)
                gll16(vbase + (size_t)(i * 4 + srow) * RS + scol, &vs[i * 4][0]);
        }
        asm volatile("s_waitcnt vmcnt(0)" ::: "memory");
        __builtin_amdgcn_sched_barrier(0);
        __syncthreads();  // both waves' tiles landed
        float s[64];
        float tmax = -3.0e38f;
        #pragma unroll
        for (int kk = 0; kk < 64; ++kk) {
            float acc = 0.0f;
            #pragma unroll
            for (int d4 = 0; d4 < 16; ++d4) {
                float4 kv = *(const float4*)&ks[kk][d4 * 4];
                acc = fmaf(q[4*d4+0], kv.x, acc);
                acc = fmaf(q[4*d4+1], kv.y, acc);
                acc = fmaf(q[4*d4+2], kv.z, acc);
                acc = fmaf(q[4*d4+3], kv.w, acc);
            }
            s[kk] = acc * scale;
            tmax = fmaxf(tmax, s[kk]);
        }
        const float mn = fmaxf(mrun, tmax);
        const float corr = __expf(mrun - mn);
        l *= corr;
        #pragma unroll
        for (int d = 0; d < 64; ++d) oa[d] *= corr;
        #pragma unroll
        for (int kk = 0; kk < 64; ++kk) {
            const float p = __expf(s[kk] - mn);
            l += p;
            #pragma unroll
            for (int d4 = 0; d4 < 16; ++d4) {
                float4 vv = *(const float4*)&vs[kk][d4 * 4];
                oa[4*d4+0] = fmaf(p, vv.x, oa[4*d4+0]);
                oa[4*d4+1] = fmaf(p, vv.y, oa[4*d4+1]);
                oa[4*d4+2] = fmaf(p, vv.z, oa[4*d4+2]);
                oa[4*d4+3] = fmaf(p, vv.w, oa[4*d4+3]);
            }
        }
        mrun = mn;
    }
    const float inv = 1.0f / l;
    u16* ohr = oh + (size_t)(b * 2048 + q0 + lane) * 1024 + h * 64;
    u16* olr = ol + (size_t)(b * 2048 + q0 + lane) * 1024 + h * 64;
    #pragma unroll
    for (int i = 0; i < 16; ++i) {
        u16x4 h4, l4;
        #pragma unroll
        for (int j = 0; j < 4; ++j) {
            u16 hh, ll; bf16_split(oa[4*i+j] * inv, hh, ll);
            h4[j] = hh; l4[j] = ll;
        }
        *(u16x4*)(ohr + i * 4) = h4;
        *(u16x4*)(olr + i * 4) = l4;
    }
}

// ---- router: logits + softmax over 8 experts (reads y planes) ----
__global__ __launch_bounds__(64)
void router_kernel(const u16* __restrict__ yh, const u16* __restrict__ yl,
                   const float* __restrict__ rw, float* __restrict__ r) {
    const int tok = blockIdx.x;
    const int lane = threadIdx.x;
    const u16* yhr = yh + (size_t)tok * DM;
    const u16* ylr = yl + (size_t)tok * DM;
    float acc[8] = {0, 0, 0, 0, 0, 0, 0, 0};
    #pragma unroll
    for (int i = 0; i < 16; ++i) {
        const int hh = i * 64 + lane;
        const float yv = bf16_comb(yhr[hh], ylr[hh]);
        const float4 w0 = *(const float4*)(rw + hh * 8);
        const float4 w1 = *(const float4*)(rw + hh * 8 + 4);
        acc[0] = fmaf(yv, w0.x, acc[0]); acc[1] = fmaf(yv, w0.y, acc[1]);
        acc[2] = fmaf(yv, w0.z, acc[2]); acc[3] = fmaf(yv, w0.w, acc[3]);
        acc[4] = fmaf(yv, w1.x, acc[4]); acc[5] = fmaf(yv, w1.y, acc[5]);
        acc[6] = fmaf(yv, w1.z, acc[6]); acc[7] = fmaf(yv, w1.w, acc[7]);
    }
    #pragma unroll
    for (int off = 32; off; off >>= 1)
        #pragma unroll
        for (int e = 0; e < 8; ++e) acc[e] += __shfl_down(acc[e], off);
    if (lane == 0) {
        float mx = acc[0];
        #pragma unroll
        for (int e = 1; e < 8; ++e) mx = fmaxf(mx, acc[e]);
        float p[8], sum = 0.0f;
        #pragma unroll
        for (int e = 0; e < 8; ++e) { p[e] = __expf(acc[e] - mx); sum += p[e]; }
        const float inv = 1.0f / sum;
        #pragma unroll
        for (int e = 0; e < 8; ++e) r[(size_t)tok * 8 + e] = p[e] * inv;
    }
}

// ---------------- launch ----------------
extern "C" void kernel_launch(void* const* d_in, const int* in_sizes, int n_in,
                              void* d_out, int out_size, void* d_ws, size_t ws_size,
                              hipStream_t stream) {
    const float* x    = (const float*)d_in[0];
    const float* ln1s = (const float*)d_in[1];
    const float* ln1b = (const float*)d_in[2];
    const float* Wqkv = (const float*)d_in[3];
    const float* bqkv = (const float*)d_in[4];
    const float* Wo   = (const float*)d_in[5];
    const float* bo   = (const float*)d_in[6];
    const float* ln2s = (const float*)d_in[7];
    const float* ln2b = (const float*)d_in[8];
    const float* rW   = (const float*)d_in[9];
    const float* We   = (const float*)d_in[10];
    const float* be   = (const float*)d_in[11];
    const float* Wmo  = (const float*)d_in[12];
    const float* bmo  = (const float*)d_in[13];
    float* out = (float*)d_out;

    char* w = (char*)d_ws;
    auto carve = [&](size_t bytes) {
        void* p = (void*)w;
        w += (bytes + 255) & ~(size_t)255;
        return p;
    };
    float* qkv   = (float*)carve((size_t)T_TOK * NQKV * 4);   // 50.3 MB (cb aliases)
    float* x1    = (float*)carve((size_t)T_TOK * DM * 4);
    u16*   y_h   = (u16*)carve((size_t)T_TOK * DM * 2);
    u16*   y_l   = (u16*)carve((size_t)T_TOK * DM * 2);
    u16*   ob_h  = (u16*)carve((size_t)T_TOK * DM * 2);
    u16*   ob_l  = (u16*)carve((size_t)T_TOK * DM * 2);
    float* r     = (float*)carve((size_t)T_TOK * 8 * 4);
    u16*   Wqkv_h = (u16*)carve((size_t)DM * NQKV * 2);
    u16*   Wqkv_l = (u16*)carve((size_t)DM * NQKV * 2);
    u16*   Wo_h   = (u16*)carve((size_t)DM * DM * 2);
    u16*   Wo_l   = (u16*)carve((size_t)DM * DM * 2);
    u16*   We_h   = (u16*)carve((size_t)8 * DM * DM * 2);
    u16*   We_l   = (u16*)carve((size_t)8 * DM * DM * 2);
    u16*   Wmo_h  = (u16*)carve((size_t)DM * DM * 2);
    u16*   Wmo_l  = (u16*)carve((size_t)DM * DM * 2);
    // cb planes alias dead qkv (qkv only read up to attention)
    u16*   cb_h  = (u16*)qkv;
    u16*   cb_l  = (u16*)qkv + (size_t)T_TOK * DM;

    // ---- weight transpose+split (every call; ~20 us, memory-bound) ----
    convert_w<<<dim3(NQKV / 64, DM / 64, 1), 256, 0, stream>>>(Wqkv, Wqkv_h, Wqkv_l, DM, NQKV);
    convert_w<<<dim3(DM / 64, DM / 64, 1), 256, 0, stream>>>(Wo, Wo_h, Wo_l, DM, DM);
    convert_w<<<dim3(DM / 64, DM / 64, 8), 256, 0, stream>>>(We, We_h, We_l, DM, DM);
    convert_w<<<dim3(DM / 64, DM / 64, 1), 256, 0, stream>>>(Wmo, Wmo_h, Wmo_l, DM, DM);

    // 1. y = LN1(x) -> planes
    ln_kernel<<<T_TOK, 256, 0, stream>>>(x, ln1s, ln1b, y_h, y_l);
    // 2. qkv = y @ Wqkv + bqkv (f32 out)
    gemm_mfma<0><<<dim3(NQKV / 128, T_TOK / 128), 256, 0, stream>>>(
        y_h, y_l, Wqkv_h, Wqkv_l, bqkv, nullptr, qkv, NQKV);
    // 3. ob = attention(qkv) -> planes
    attn_kernel<<<dim3(16, 32), 128, 0, stream>>>(qkv, ob_h, ob_l);
    // 4. x1 = x + ob @ Wo + bo
    gemm_mfma<1><<<dim3(DM / 128, T_TOK / 128), 256, 0, stream>>>(
        ob_h, ob_l, Wo_h, Wo_l, bo, x, x1, DM);
    // 5. y = LN2(x1) -> planes
    ln_kernel<<<T_TOK, 256, 0, stream>>>(x1, ln2s, ln2b, y_h, y_l);
    // 6. r = softmax(y @ rW)
    router_kernel<<<T_TOK, 64, 0, stream>>>(y_h, y_l, rW, r);
    // 7. comb = sum_e r_e * (y @ We[e] + be[e]) -> planes (aliases qkv)
    moe_gemm<<<dim3(DM / 64, T_TOK / 128), 256, 0, stream>>>(
        y_h, y_l, We_h, We_l, be, r, cb_h, cb_l);
    // 8. out = x1 + comb @ Wmo + bmo
    gemm_mfma<1><<<dim3(DM / 128, T_TOK / 128), 256, 0, stream>>>(
        cb_h, cb_l, Wmo_h, Wmo_l, bmo, x1, out, DM);
}

// Round 5
// 887.535 us; speedup vs baseline: 3.4379x; 3.4379x over previous
//
#include <hip/hip_runtime.h>
#include <hip/hip_bf16.h>

typedef unsigned short u16;
typedef float f32x4 __attribute__((ext_vector_type(4)));
typedef short s16x8 __attribute__((ext_vector_type(8)));
typedef unsigned short u16x4 __attribute__((ext_vector_type(4)));
typedef unsigned short u16x8 __attribute__((ext_vector_type(8)));

#define T_TOK 4096
#define DM 1024
#define NQKV 3072
#define LN_EPS 1e-6f
#define KDIM 1024
#define NT 32  // KDIM / 32 k-tiles

// ---- async global->LDS, 16B per lane. LDS dest = uniform base + lane*16. ----
__device__ __forceinline__ void gll16(const void* g, void* l) {
    __builtin_amdgcn_global_load_lds(
        (const __attribute__((address_space(1))) void*)g,
        (__attribute__((address_space(3))) void*)l, 16, 0, 0);
}

// ---- XCD-aware block swizzle (requires gx*gy % 8 == 0; all our grids comply) ----
__device__ __forceinline__ void xcd_swz(int& bx, int& by) {
    const int gx = gridDim.x, gy = gridDim.y;
    const int nwg = gx * gy;
    const int lin = by * gx + bx;
    const int cpx = nwg >> 3;
    const int swz = (lin & 7) * cpx + (lin >> 3);
    bx = swz % gx;
    by = swz / gx;
}

// ---- bf16 split: x ~= hi + lo, each RNE bf16. |err| <= ~2^-17 |x| ----
__device__ __forceinline__ void bf16_split(float x, u16& hi, u16& lo) {
    unsigned xb = __float_as_uint(x);
    unsigned rh = xb + 0x7fffu + ((xb >> 16) & 1u);
    hi = (u16)(rh >> 16);
    float hf = __uint_as_float(((unsigned)hi) << 16);
    float rs = x - hf;
    unsigned rb = __float_as_uint(rs);
    unsigned rl = rb + 0x7fffu + ((rb >> 16) & 1u);
    lo = (u16)(rl >> 16);
}
__device__ __forceinline__ float bf16_comb(u16 h, u16 l) {
    return __uint_as_float(((unsigned)h) << 16) + __uint_as_float(((unsigned)l) << 16);
}

// 3-pass split MFMA: acc += ah*bh + ah*bl + al*bh
#define MFMA3(ACC, AH, AL, BH, BL) { \
    ACC = __builtin_amdgcn_mfma_f32_16x16x32_bf16(AH, BH, ACC, 0, 0, 0); \
    ACC = __builtin_amdgcn_mfma_f32_16x16x32_bf16(AH, BL, ACC, 0, 0, 0); \
    ACC = __builtin_amdgcn_mfma_f32_16x16x32_bf16(AL, BH, ACC, 0, 0, 0); }

// ---- weight transpose + split: src [K][N] f32 (batch z) -> dh/dl [N][K] bf16 ----
__global__ __launch_bounds__(256)
void convert_w(const float* __restrict__ src, u16* __restrict__ dh,
               u16* __restrict__ dl, int K, int N) {
    const int e = blockIdx.z;
    src += (size_t)e * K * N;
    dh  += (size_t)e * K * N;
    dl  += (size_t)e * K * N;
    __shared__ float ts[64][65];
    const int t = threadIdx.x;
    const int k0 = blockIdx.y * 64, n0 = blockIdx.x * 64;
    const int r = t >> 4, c4 = (t & 15) * 4;
    #pragma unroll
    for (int i = 0; i < 4; ++i) {
        const int kr = r + i * 16;
        float4 v = *(const float4*)(src + (size_t)(k0 + kr) * N + n0 + c4);
        ts[kr][c4 + 0] = v.x; ts[kr][c4 + 1] = v.y;
        ts[kr][c4 + 2] = v.z; ts[kr][c4 + 3] = v.w;
    }
    __syncthreads();
    #pragma unroll
    for (int i = 0; i < 4; ++i) {
        const int nr = r + i * 16;
        u16x4 h4, l4;
        #pragma unroll
        for (int j = 0; j < 4; ++j) {
            u16 h, l; bf16_split(ts[c4 + j][nr], h, l);
            h4[j] = h; l4[j] = l;
        }
        *(u16x4*)(dh + (size_t)(n0 + nr) * K + k0 + c4) = h4;
        *(u16x4*)(dl + (size_t)(n0 + nr) * K + k0 + c4) = l4;
    }
}

// ---- LayerNorm -> bf16 hi/lo planes ----
__global__ __launch_bounds__(256)
void ln_kernel(const float* __restrict__ x, const float* __restrict__ sc,
               const float* __restrict__ bi, u16* __restrict__ yh,
               u16* __restrict__ yl) {
    const int row = blockIdx.x;
    const int t = threadIdx.x;
    const float* xr = x + (size_t)row * DM;
    float4 v = *(const float4*)(xr + t * 4);
    float s  = v.x + v.y + v.z + v.w;
    float s2 = v.x*v.x + v.y*v.y + v.z*v.z + v.w*v.w;
    #pragma unroll
    for (int off = 32; off; off >>= 1) {
        s  += __shfl_down(s, off);
        s2 += __shfl_down(s2, off);
    }
    __shared__ float ss[4], ss2[4];
    const int wid = t >> 6;
    if ((t & 63) == 0) { ss[wid] = s; ss2[wid] = s2; }
    __syncthreads();
    const float tot  = ss[0] + ss[1] + ss[2] + ss[3];
    const float tot2 = ss2[0] + ss2[1] + ss2[2] + ss2[3];
    const float mu  = tot * (1.0f / DM);
    const float var = tot2 * (1.0f / DM) - mu * mu;
    const float rcp = rsqrtf(var + LN_EPS);
    float4 sv = *(const float4*)(sc + t * 4);
    float4 bv = *(const float4*)(bi + t * 4);
    float o[4];
    o[0] = (v.x - mu) * rcp * sv.x + bv.x;
    o[1] = (v.y - mu) * rcp * sv.y + bv.y;
    o[2] = (v.z - mu) * rcp * sv.z + bv.z;
    o[3] = (v.w - mu) * rcp * sv.w + bv.w;
    u16x4 h4, l4;
    #pragma unroll
    for (int j = 0; j < 4; ++j) { u16 h, l; bf16_split(o[j], h, l); h4[j] = h; l4[j] = l; }
    *(u16x4*)(yh + (size_t)row * DM + t * 4) = h4;
    *(u16x4*)(yl + (size_t)row * DM + t * 4) = l4;
}

// ---- QKV GEMM 128x128x32: planes out [b,h,s,d] hi/lo for q,k,v ----
__global__ __launch_bounds__(256, 2)
void qkv_gemm(const u16* __restrict__ Ah, const u16* __restrict__ Al,
              const u16* __restrict__ Bh, const u16* __restrict__ Bl,
              const float* __restrict__ bias,
              u16* __restrict__ qh, u16* __restrict__ ql,
              u16* __restrict__ kh, u16* __restrict__ kl,
              u16* __restrict__ vh, u16* __restrict__ vl) {
    __shared__ __align__(16) u16 Ahs[128 * 32], Als[128 * 32];
    __shared__ __align__(16) u16 Bhs[128 * 32], Bls[128 * 32];
    int bx = blockIdx.x, by = blockIdx.y;
    xcd_swz(bx, by);
    const int t = threadIdx.x;
    const int m0 = by * 128, n0 = bx * 128;
    const int lane = t & 63, wid = t >> 6;
    const int wm = wid >> 1, wn = wid & 1;
    const int lr = lane & 15, lc = lane >> 4;
    const int srow = lane >> 2, skk = (lane & 3) * 8;
    const int w32 = wid * 32;
    const u16* Agh = Ah + (size_t)(m0 + w32 + srow) * KDIM + skk;
    const u16* Agl = Al + (size_t)(m0 + w32 + srow) * KDIM + skk;
    const u16* Bgh = Bh + (size_t)(n0 + w32 + srow) * KDIM + skk;
    const u16* Bgl = Bl + (size_t)(n0 + w32 + srow) * KDIM + skk;

    f32x4 acc[4][4];
    #pragma unroll
    for (int i = 0; i < 4; ++i)
        #pragma unroll
        for (int j = 0; j < 4; ++j)
            #pragma unroll
            for (int r = 0; r < 4; ++r) acc[i][j][r] = 0.0f;

    for (int kt = 0; kt < NT; ++kt) {
        const int ko = kt * 32;
        gll16(Agh + ko,              &Ahs[w32 * 32]);
        gll16(Agh + ko + 16 * KDIM,  &Ahs[(w32 + 16) * 32]);
        gll16(Agl + ko,              &Als[w32 * 32]);
        gll16(Agl + ko + 16 * KDIM,  &Als[(w32 + 16) * 32]);
        gll16(Bgh + ko,              &Bhs[w32 * 32]);
        gll16(Bgh + ko + 16 * KDIM,  &Bhs[(w32 + 16) * 32]);
        gll16(Bgl + ko,              &Bls[w32 * 32]);
        gll16(Bgl + ko + 16 * KDIM,  &Bls[(w32 + 16) * 32]);
        __syncthreads();
        s16x8 fa_h[4], fa_l[4], fb_h[4], fb_l[4];
        #pragma unroll
        for (int fi = 0; fi < 4; ++fi) {
            const int ro = (wm * 64 + fi * 16 + lr) * 32 + lc * 8;
            fa_h[fi] = *(const s16x8*)&Ahs[ro];
            fa_l[fi] = *(const s16x8*)&Als[ro];
        }
        #pragma unroll
        for (int fj = 0; fj < 4; ++fj) {
            const int ro = (wn * 64 + fj * 16 + lr) * 32 + lc * 8;
            fb_h[fj] = *(const s16x8*)&Bhs[ro];
            fb_l[fj] = *(const s16x8*)&Bls[ro];
        }
        #pragma unroll
        for (int fi = 0; fi < 4; ++fi)
            #pragma unroll
            for (int fj = 0; fj < 4; ++fj)
                MFMA3(acc[fi][fj], fa_h[fi], fa_l[fi], fb_h[fj], fb_l[fj])
        __syncthreads();
    }

    #pragma unroll
    for (int fj = 0; fj < 4; ++fj) {
        const int col = n0 + wn * 64 + fj * 16 + lr;
        const int sec = col >> 10;              // 0=q 1=k 2=v
        const int hh = (col & 1023) >> 6;
        const int dd = col & 63;
        const float bv = bias[col];
        u16* ph = (sec == 0) ? qh : (sec == 1) ? kh : vh;
        u16* pl = (sec == 0) ? ql : (sec == 1) ? kl : vl;
        #pragma unroll
        for (int fi = 0; fi < 4; ++fi)
            #pragma unroll
            for (int r = 0; r < 4; ++r) {
                const int row = m0 + wm * 64 + fi * 16 + lc * 4 + r;
                const int b = row >> 11, s = row & 2047;
                const size_t idx = ((size_t)(b * 16 + hh) * 2048 + s) * 64 + dd;
                u16 h, l; bf16_split(acc[fi][fj][r] + bv, h, l);
                ph[idx] = h; pl[idx] = l;
            }
    }
}

// ---- MFMA GEMM 128x128x32, gll staging. A [M][K] planes, B [N][K] planes ----
// C = A@B^T + bias + res (f32 out)
__global__ __launch_bounds__(256, 2)
void gemm_mfma(const u16* __restrict__ Ah, const u16* __restrict__ Al,
               const u16* __restrict__ Bh, const u16* __restrict__ Bl,
               const float* __restrict__ bias, const float* __restrict__ res,
               float* __restrict__ C, int N) {
    __shared__ __align__(16) u16 Ahs[128 * 32], Als[128 * 32];
    __shared__ __align__(16) u16 Bhs[128 * 32], Bls[128 * 32];
    int bx = blockIdx.x, by = blockIdx.y;
    xcd_swz(bx, by);
    const int t = threadIdx.x;
    const int m0 = by * 128, n0 = bx * 128;
    const int lane = t & 63, wid = t >> 6;
    const int wm = wid >> 1, wn = wid & 1;
    const int lr = lane & 15, lc = lane >> 4;
    const int srow = lane >> 2, skk = (lane & 3) * 8;
    const int w32 = wid * 32;
    const u16* Agh = Ah + (size_t)(m0 + w32 + srow) * KDIM + skk;
    const u16* Agl = Al + (size_t)(m0 + w32 + srow) * KDIM + skk;
    const u16* Bgh = Bh + (size_t)(n0 + w32 + srow) * KDIM + skk;
    const u16* Bgl = Bl + (size_t)(n0 + w32 + srow) * KDIM + skk;

    f32x4 acc[4][4];
    #pragma unroll
    for (int i = 0; i < 4; ++i)
        #pragma unroll
        for (int j = 0; j < 4; ++j)
            #pragma unroll
            for (int r = 0; r < 4; ++r) acc[i][j][r] = 0.0f;

    for (int kt = 0; kt < NT; ++kt) {
        const int ko = kt * 32;
        gll16(Agh + ko,              &Ahs[w32 * 32]);
        gll16(Agh + ko + 16 * KDIM,  &Ahs[(w32 + 16) * 32]);
        gll16(Agl + ko,              &Als[w32 * 32]);
        gll16(Agl + ko + 16 * KDIM,  &Als[(w32 + 16) * 32]);
        gll16(Bgh + ko,              &Bhs[w32 * 32]);
        gll16(Bgh + ko + 16 * KDIM,  &Bhs[(w32 + 16) * 32]);
        gll16(Bgl + ko,              &Bls[w32 * 32]);
        gll16(Bgl + ko + 16 * KDIM,  &Bls[(w32 + 16) * 32]);
        __syncthreads();
        s16x8 fa_h[4], fa_l[4], fb_h[4], fb_l[4];
        #pragma unroll
        for (int fi = 0; fi < 4; ++fi) {
            const int ro = (wm * 64 + fi * 16 + lr) * 32 + lc * 8;
            fa_h[fi] = *(const s16x8*)&Ahs[ro];
            fa_l[fi] = *(const s16x8*)&Als[ro];
        }
        #pragma unroll
        for (int fj = 0; fj < 4; ++fj) {
            const int ro = (wn * 64 + fj * 16 + lr) * 32 + lc * 8;
            fb_h[fj] = *(const s16x8*)&Bhs[ro];
            fb_l[fj] = *(const s16x8*)&Bls[ro];
        }
        #pragma unroll
        for (int fi = 0; fi < 4; ++fi)
            #pragma unroll
            for (int fj = 0; fj < 4; ++fj)
                MFMA3(acc[fi][fj], fa_h[fi], fa_l[fi], fb_h[fj], fb_l[fj])
        __syncthreads();
    }

    #pragma unroll
    for (int fj = 0; fj < 4; ++fj) {
        const int col = n0 + wn * 64 + fj * 16 + lr;
        const float bv = bias[col];
        #pragma unroll
        for (int fi = 0; fi < 4; ++fi)
            #pragma unroll
            for (int r = 0; r < 4; ++r) {
                const int row = m0 + wm * 64 + fi * 16 + lc * 4 + r;
                float v = acc[fi][fj][r] + bv + res[(size_t)row * N + col];
                C[(size_t)row * N + col] = v;
            }
    }
}

// ---- MoE GEMM 128x64x32: comb = sum_e r[:,e]*(y@We[e]^T + be[e]) -> planes ----
__global__ __launch_bounds__(256, 2)
void moe_gemm(const u16* __restrict__ Ah, const u16* __restrict__ Al,
              const u16* __restrict__ Bh, const u16* __restrict__ Bl,
              const float* __restrict__ be, const float* __restrict__ gate,
              u16* __restrict__ Ch, u16* __restrict__ Cl) {
    __shared__ __align__(16) u16 Ahs[128 * 32], Als[128 * 32];
    __shared__ __align__(16) u16 Bhs[64 * 32],  Bls[64 * 32];
    int bx = blockIdx.x, by = blockIdx.y;
    xcd_swz(bx, by);
    const int t = threadIdx.x;
    const int m0 = by * 128, n0 = bx * 64;
    const int lane = t & 63, wid = t >> 6;
    const int wm = wid >> 1, wn = wid & 1;
    const int lr = lane & 15, lc = lane >> 4;
    const int srow = lane >> 2, skk = (lane & 3) * 8;
    const int w32 = wid * 32, w16 = wid * 16;
    const u16* Agh = Ah + (size_t)(m0 + w32 + srow) * KDIM + skk;
    const u16* Agl = Al + (size_t)(m0 + w32 + srow) * KDIM + skk;

    f32x4 out[4][2];
    #pragma unroll
    for (int i = 0; i < 4; ++i)
        #pragma unroll
        for (int j = 0; j < 2; ++j)
            #pragma unroll
            for (int r = 0; r < 4; ++r) out[i][j][r] = 0.0f;

    for (int e = 0; e < 8; ++e) {
        const u16* Bgh = Bh + ((size_t)e << 20) + (size_t)(n0 + w16 + srow) * KDIM + skk;
        const u16* Bgl = Bl + ((size_t)e << 20) + (size_t)(n0 + w16 + srow) * KDIM + skk;
        f32x4 acc[4][2];
        #pragma unroll
        for (int i = 0; i < 4; ++i)
            #pragma unroll
            for (int j = 0; j < 2; ++j)
                #pragma unroll
                for (int r = 0; r < 4; ++r) acc[i][j][r] = 0.0f;

        for (int kt = 0; kt < NT; ++kt) {
            const int ko = kt * 32;
            gll16(Agh + ko,             &Ahs[w32 * 32]);
            gll16(Agh + ko + 16 * KDIM, &Ahs[(w32 + 16) * 32]);
            gll16(Agl + ko,             &Als[w32 * 32]);
            gll16(Agl + ko + 16 * KDIM, &Als[(w32 + 16) * 32]);
            gll16(Bgh + ko,             &Bhs[w16 * 32]);
            gll16(Bgl + ko,             &Bls[w16 * 32]);
            __syncthreads();
            s16x8 fa_h[4], fa_l[4], fb_h[2], fb_l[2];
            #pragma unroll
            for (int fi = 0; fi < 4; ++fi) {
                const int ro = (wm * 64 + fi * 16 + lr) * 32 + lc * 8;
                fa_h[fi] = *(const s16x8*)&Ahs[ro];
                fa_l[fi] = *(const s16x8*)&Als[ro];
            }
            #pragma unroll
            for (int fj = 0; fj < 2; ++fj) {
                const int ro = (wn * 32 + fj * 16 + lr) * 32 + lc * 8;
                fb_h[fj] = *(const s16x8*)&Bhs[ro];
                fb_l[fj] = *(const s16x8*)&Bls[ro];
            }
            #pragma unroll
            for (int fi = 0; fi < 4; ++fi)
                #pragma unroll
                for (int fj = 0; fj < 2; ++fj)
                    MFMA3(acc[fi][fj], fa_h[fi], fa_l[fi], fb_h[fj], fb_l[fj])
            __syncthreads();
        }
        float bv[2];
        #pragma unroll
        for (int fj = 0; fj < 2; ++fj)
            bv[fj] = be[e * 1024 + n0 + wn * 32 + fj * 16 + lr];
        #pragma unroll
        for (int fi = 0; fi < 4; ++fi)
            #pragma unroll
            for (int r = 0; r < 4; ++r) {
                const int row = m0 + wm * 64 + fi * 16 + lc * 4 + r;
                const float g = gate[(size_t)row * 8 + e];
                #pragma unroll
                for (int fj = 0; fj < 2; ++fj)
                    out[fi][fj][r] += g * (acc[fi][fj][r] + bv[fj]);
            }
    }
    #pragma unroll
    for (int fi = 0; fi < 4; ++fi)
        #pragma unroll
        for (int fj = 0; fj < 2; ++fj) {
            const int col = n0 + wn * 32 + fj * 16 + lr;
            #pragma unroll
            for (int r = 0; r < 4; ++r) {
                const int row = m0 + wm * 64 + fi * 16 + lc * 4 + r;
                u16 h, l; bf16_split(out[fi][fj][r], h, l);
                Ch[(size_t)row * 1024 + col] = h;
                Cl[(size_t)row * 1024 + col] = l;
            }
        }
}

// ---- MFMA flash attention: bf16 hi/lo, online softmax, 4 waves x 16 q-rows ----
// K_lds [64 rows][64 d] XOR-swizzled (byte ^= (row&7)<<4); Vt_lds [64 d][72 k];
// P_lds per-wave [16 q][72 k].
#define VTS 72
__global__ __launch_bounds__(256, 3)
void attn_kernel(const u16* __restrict__ qh, const u16* __restrict__ ql,
                 const u16* __restrict__ kh, const u16* __restrict__ kl,
                 const u16* __restrict__ vh, const u16* __restrict__ vl,
                 u16* __restrict__ oh, u16* __restrict__ ol) {
    __shared__ __align__(16) u16 Khs[64 * 64], Kls[64 * 64];
    __shared__ __align__(16) u16 Vth[64 * VTS], Vtl[64 * VTS];
    __shared__ __align__(16) u16 Phs[4 * 16 * VTS], Pls[4 * 16 * VTS];
    const int t = threadIdx.x;
    const int lane = t & 63, w = t >> 6;
    const int lr = lane & 15, lc = lane >> 4;
    const int q0 = blockIdx.x * 64;
    const int bh = blockIdx.y;
    const int b = bh >> 4, h = bh & 15;
    const size_t head = (size_t)bh * 2048 * 64;

    // Q fragments (A-frag: row = lr, d = c*32 + lc*8), rows q0 + w*16 + lr
    s16x8 qf_h[2], qf_l[2];
    {
        const size_t qrow = head + (size_t)(q0 + w * 16 + lr) * 64;
        #pragma unroll
        for (int c = 0; c < 2; ++c) {
            qf_h[c] = *(const s16x8*)(qh + qrow + c * 32 + lc * 8);
            qf_l[c] = *(const s16x8*)(ql + qrow + c * 32 + lc * 8);
        }
    }

    f32x4 o4[4];
    #pragma unroll
    for (int dt = 0; dt < 4; ++dt)
        #pragma unroll
        for (int r = 0; r < 4; ++r) o4[dt][r] = 0.0f;
    float m_run[4], l_run[4];
    #pragma unroll
    for (int r = 0; r < 4; ++r) { m_run[r] = -3.0e38f; l_run[r] = 0.0f; }

    char* const kbase_h = (char*)Khs;
    char* const kbase_l = (char*)Kls;
    u16* const pmy_h = Phs + w * 16 * VTS;
    u16* const pmy_l = Pls + w * 16 * VTS;

    for (int kt = 0; kt < 32; ++kt) {
        __syncthreads();  // previous tile fully consumed
        // ---- stage K (swizzled rows) and V^T ----
        {
            const size_t grow = head + (size_t)(kt * 64 + lane) * 64;
            const int dbase = (w & 1) * 32;
            const u16* ksrc = ((w >> 1) ? kl : kh) + grow + dbase;
            char* kdst = (w >> 1) ? kbase_l : kbase_h;
            #pragma unroll
            for (int jj = 0; jj < 4; ++jj) {
                u16x8 kv = *(const u16x8*)(ksrc + jj * 8);
                const int off = (lane * 128 + dbase * 2 + jj * 16) ^ ((lane & 7) << 4);
                *(u16x8*)(kdst + off) = kv;
            }
            const u16* vsrc = ((w >> 1) ? vl : vh) + grow + dbase;
            u16* vdst = (w >> 1) ? Vtl : Vth;
            #pragma unroll
            for (int jj = 0; jj < 4; ++jj) {
                u16x8 vv = *(const u16x8*)(vsrc + jj * 8);
                #pragma unroll
                for (int i = 0; i < 8; ++i)
                    vdst[(dbase + jj * 8 + i) * VTS + lane] = vv[i];
            }
        }
        __syncthreads();

        // ---- S = Q K^T (3-pass), tiles j: k = j*16 + lr ----
        f32x4 s4[4];
        const int kxor = (lr & 7) << 4;
        #pragma unroll
        for (int j = 0; j < 4; ++j) {
            #pragma unroll
            for (int r = 0; r < 4; ++r) s4[j][r] = 0.0f;
            #pragma unroll
            for (int c = 0; c < 2; ++c) {
                const int off = ((j * 16 + lr) * 128 + c * 64 + lc * 16) ^ kxor;
                s16x8 kb_h = *(const s16x8*)(kbase_h + off);
                s16x8 kb_l = *(const s16x8*)(kbase_l + off);
                MFMA3(s4[j], qf_h[c], qf_l[c], kb_h, kb_l)
            }
        }
        // ---- online softmax (rows q = lc*4 + r; reduce over lr-group) ----
        #pragma unroll
        for (int j = 0; j < 4; ++j)
            #pragma unroll
            for (int r = 0; r < 4; ++r) s4[j][r] *= 0.125f;
        #pragma unroll
        for (int r = 0; r < 4; ++r) {
            float tm = fmaxf(fmaxf(s4[0][r], s4[1][r]), fmaxf(s4[2][r], s4[3][r]));
            tm = fmaxf(tm, __shfl_xor(tm, 1));
            tm = fmaxf(tm, __shfl_xor(tm, 2));
            tm = fmaxf(tm, __shfl_xor(tm, 4));
            tm = fmaxf(tm, __shfl_xor(tm, 8));
            const float mn = fmaxf(m_run[r], tm);
            const float corr = __expf(m_run[r] - mn);
            m_run[r] = mn;
            float ps = 0.0f;
            #pragma unroll
            for (int j = 0; j < 4; ++j) {
                const float p = __expf(s4[j][r] - mn);
                s4[j][r] = p;
                ps += p;
            }
            ps += __shfl_xor(ps, 1);
            ps += __shfl_xor(ps, 2);
            ps += __shfl_xor(ps, 4);
            ps += __shfl_xor(ps, 8);
            l_run[r] = l_run[r] * corr + ps;
            #pragma unroll
            for (int dt = 0; dt < 4; ++dt) o4[dt][r] *= corr;
        }
        // ---- write P hi/lo to per-wave LDS [q][VTS] ----
        #pragma unroll
        for (int j = 0; j < 4; ++j)
            #pragma unroll
            for (int r = 0; r < 4; ++r) {
                u16 ph, pl; bf16_split(s4[j][r], ph, pl);
                const int pidx = (lc * 4 + r) * VTS + j * 16 + lr;
                pmy_h[pidx] = ph;
                pmy_l[pidx] = pl;
            }
        // ---- O += P V (3-pass): A = P rows q=lr, B = Vt cols d ----
        #pragma unroll
        for (int kc = 0; kc < 2; ++kc) {
            const int pbase = lr * VTS + kc * 32 + lc * 8;
            s16x8 pa_h = *(const s16x8*)(pmy_h + pbase);
            s16x8 pa_l = *(const s16x8*)(pmy_l + pbase);
            #pragma unroll
            for (int dt = 0; dt < 4; ++dt) {
                const int vbase = (dt * 16 + lr) * VTS + kc * 32 + lc * 8;
                s16x8 vb_h = *(const s16x8*)(Vth + vbase);
                s16x8 vb_l = *(const s16x8*)(Vtl + vbase);
                MFMA3(o4[dt], pa_h, pa_l, vb_h, vb_l)
            }
        }
    }

    // ---- epilogue: normalize, split, store (rows q = lc*4+r, cols d = dt*16+lr) ----
    float inv[4];
    #pragma unroll
    for (int r = 0; r < 4; ++r) inv[r] = 1.0f / l_run[r];
    #pragma unroll
    for (int dt = 0; dt < 4; ++dt)
        #pragma unroll
        for (int r = 0; r < 4; ++r) {
            const int tok = b * 2048 + q0 + w * 16 + lc * 4 + r;
            const size_t idx = (size_t)tok * 1024 + h * 64 + dt * 16 + lr;
            u16 hh, ll; bf16_split(o4[dt][r] * inv[r], hh, ll);
            oh[idx] = hh; ol[idx] = ll;
        }
}

// ---- router: logits + softmax over 8 experts (reads y planes) ----
__global__ __launch_bounds__(64)
void router_kernel(const u16* __restrict__ yh, const u16* __restrict__ yl,
                   const float* __restrict__ rw, float* __restrict__ r) {
    const int tok = blockIdx.x;
    const int lane = threadIdx.x;
    const u16* yhr = yh + (size_t)tok * DM;
    const u16* ylr = yl + (size_t)tok * DM;
    float acc[8] = {0, 0, 0, 0, 0, 0, 0, 0};
    #pragma unroll
    for (int i = 0; i < 16; ++i) {
        const int hh = i * 64 + lane;
        const float yv = bf16_comb(yhr[hh], ylr[hh]);
        const float4 w0 = *(const float4*)(rw + hh * 8);
        const float4 w1 = *(const float4*)(rw + hh * 8 + 4);
        acc[0] = fmaf(yv, w0.x, acc[0]); acc[1] = fmaf(yv, w0.y, acc[1]);
        acc[2] = fmaf(yv, w0.z, acc[2]); acc[3] = fmaf(yv, w0.w, acc[3]);
        acc[4] = fmaf(yv, w1.x, acc[4]); acc[5] = fmaf(yv, w1.y, acc[5]);
        acc[6] = fmaf(yv, w1.z, acc[6]); acc[7] = fmaf(yv, w1.w, acc[7]);
    }
    #pragma unroll
    for (int off = 32; off; off >>= 1)
        #pragma unroll
        for (int e = 0; e < 8; ++e) acc[e] += __shfl_down(acc[e], off);
    if (lane == 0) {
        float mx = acc[0];
        #pragma unroll
        for (int e = 1; e < 8; ++e) mx = fmaxf(mx, acc[e]);
        float p[8], sum = 0.0f;
        #pragma unroll
        for (int e = 0; e < 8; ++e) { p[e] = __expf(acc[e] - mx); sum += p[e]; }
        const float inv = 1.0f / sum;
        #pragma unroll
        for (int e = 0; e < 8; ++e) r[(size_t)tok * 8 + e] = p[e] * inv;
    }
}

// ---------------- launch ----------------
extern "C" void kernel_launch(void* const* d_in, const int* in_sizes, int n_in,
                              void* d_out, int out_size, void* d_ws, size_t ws_size,
                              hipStream_t stream) {
    const float* x    = (const float*)d_in[0];
    const float* ln1s = (const float*)d_in[1];
    const float* ln1b = (const float*)d_in[2];
    const float* Wqkv = (const float*)d_in[3];
    const float* bqkv = (const float*)d_in[4];
    const float* Wo   = (const float*)d_in[5];
    const float* bo   = (const float*)d_in[6];
    const float* ln2s = (const float*)d_in[7];
    const float* ln2b = (const float*)d_in[8];
    const float* rW   = (const float*)d_in[9];
    const float* We   = (const float*)d_in[10];
    const float* be   = (const float*)d_in[11];
    const float* Wmo  = (const float*)d_in[12];
    const float* bmo  = (const float*)d_in[13];
    float* out = (float*)d_out;

    char* w = (char*)d_ws;
    auto carve = [&](size_t bytes) {
        void* p = (void*)w;
        w += (bytes + 255) & ~(size_t)255;
        return p;
    };
    const size_t PL = (size_t)T_TOK * DM;  // 4M elements per plane
    u16* qh = (u16*)carve(PL * 2); u16* ql = (u16*)carve(PL * 2);
    u16* kh = (u16*)carve(PL * 2); u16* kl = (u16*)carve(PL * 2);
    u16* vh = (u16*)carve(PL * 2); u16* vl = (u16*)carve(PL * 2);
    float* x1  = (float*)carve(PL * 4);
    u16* y_h  = (u16*)carve(PL * 2); u16* y_l  = (u16*)carve(PL * 2);
    u16* ob_h = (u16*)carve(PL * 2); u16* ob_l = (u16*)carve(PL * 2);
    float* r  = (float*)carve((size_t)T_TOK * 8 * 4);
    u16* Wqkv_h = (u16*)carve((size_t)DM * NQKV * 2);
    u16* Wqkv_l = (u16*)carve((size_t)DM * NQKV * 2);
    u16* Wo_h   = (u16*)carve((size_t)DM * DM * 2);
    u16* Wo_l   = (u16*)carve((size_t)DM * DM * 2);
    u16* We_h   = (u16*)carve((size_t)8 * DM * DM * 2);
    u16* We_l   = (u16*)carve((size_t)8 * DM * DM * 2);
    u16* Wmo_h  = (u16*)carve((size_t)DM * DM * 2);
    u16* Wmo_l  = (u16*)carve((size_t)DM * DM * 2);
    // cb planes alias q planes (dead after attention)
    u16* cb_h = qh;
    u16* cb_l = ql;

    // ---- weight transpose+split ----
    convert_w<<<dim3(NQKV / 64, DM / 64, 1), 256, 0, stream>>>(Wqkv, Wqkv_h, Wqkv_l, DM, NQKV);
    convert_w<<<dim3(DM / 64, DM / 64, 1), 256, 0, stream>>>(Wo, Wo_h, Wo_l, DM, DM);
    convert_w<<<dim3(DM / 64, DM / 64, 8), 256, 0, stream>>>(We, We_h, We_l, DM, DM);
    convert_w<<<dim3(DM / 64, DM / 64, 1), 256, 0, stream>>>(Wmo, Wmo_h, Wmo_l, DM, DM);

    // 1. y = LN1(x) -> planes
    ln_kernel<<<T_TOK, 256, 0, stream>>>(x, ln1s, ln1b, y_h, y_l);
    // 2. q/k/v planes = split(y @ Wqkv + bqkv) in [b,h,s,d]
    qkv_gemm<<<dim3(NQKV / 128, T_TOK / 128), 256, 0, stream>>>(
        y_h, y_l, Wqkv_h, Wqkv_l, bqkv, qh, ql, kh, kl, vh, vl);
    // 3. ob = attention(q,k,v) -> planes
    attn_kernel<<<dim3(32, 32), 256, 0, stream>>>(qh, ql, kh, kl, vh, vl, ob_h, ob_l);
    // 4. x1 = x + ob @ Wo + bo
    gemm_mfma<<<dim3(DM / 128, T_TOK / 128), 256, 0, stream>>>(
        ob_h, ob_l, Wo_h, Wo_l, bo, x, x1, DM);
    // 5. y = LN2(x1) -> planes
    ln_kernel<<<T_TOK, 256, 0, stream>>>(x1, ln2s, ln2b, y_h, y_l);
    // 6. r = softmax(y @ rW)
    router_kernel<<<T_TOK, 64, 0, stream>>>(y_h, y_l, rW, r);
    // 7. comb = sum_e r_e * (y @ We[e] + be[e]) -> planes (aliases q planes)
    moe_gemm<<<dim3(DM / 64, T_TOK / 128), 256, 0, stream>>>(
        y_h, y_l, We_h, We_l, be, r, cb_h, cb_l);
    // 8. out = x1 + comb @ Wmo + bmo
    gemm_mfma<<<dim3(DM / 128, T_TOK / 128), 256, 0, stream>>>(
        cb_h, cb_l, Wmo_h, Wmo_l, bmo, x1, out, DM);
}

// Round 7
// 824.711 us; speedup vs baseline: 3.6998x; 1.0762x over previous
//
#include <hip/hip_runtime.h>
#include <hip/hip_bf16.h>

typedef unsigned short u16;
typedef float f32x4 __attribute__((ext_vector_type(4)));
typedef short s16x8 __attribute__((ext_vector_type(8)));
typedef unsigned short u16x4 __attribute__((ext_vector_type(4)));
typedef unsigned short u16x8 __attribute__((ext_vector_type(8)));

#define T_TOK 4096
#define DM 1024
#define NQKV 3072
#define LN_EPS 1e-6f
#define KDIM 1024
#define NT 32  // KDIM / 32 k-tiles

// ---- async global->LDS, 16B per lane. LDS dest = uniform base + lane*16. ----
__device__ __forceinline__ void gll16(const void* g, void* l) {
    __builtin_amdgcn_global_load_lds(
        (const __attribute__((address_space(1))) void*)g,
        (__attribute__((address_space(3))) void*)l, 16, 0, 0);
}

// ---- XCD-aware block swizzle (requires gx*gy % 8 == 0; all our grids comply) ----
__device__ __forceinline__ void xcd_swz(int& bx, int& by) {
    const int gx = gridDim.x, gy = gridDim.y;
    const int nwg = gx * gy;
    const int lin = by * gx + bx;
    const int cpx = nwg >> 3;
    const int swz = (lin & 7) * cpx + (lin >> 3);
    bx = swz % gx;
    by = swz / gx;
}

// ---- bf16 split: x ~= hi + lo, each RNE bf16. |err| <= ~2^-17 |x| ----
__device__ __forceinline__ void bf16_split(float x, u16& hi, u16& lo) {
    unsigned xb = __float_as_uint(x);
    unsigned rh = xb + 0x7fffu + ((xb >> 16) & 1u);
    hi = (u16)(rh >> 16);
    float hf = __uint_as_float(((unsigned)hi) << 16);
    float rs = x - hf;
    unsigned rb = __float_as_uint(rs);
    unsigned rl = rb + 0x7fffu + ((rb >> 16) & 1u);
    lo = (u16)(rl >> 16);
}
__device__ __forceinline__ u16 f2bf(float x) {  // RNE to single bf16
    unsigned xb = __float_as_uint(x);
    return (u16)((xb + 0x7fffu + ((xb >> 16) & 1u)) >> 16);
}
__device__ __forceinline__ float bf16_comb(u16 h, u16 l) {
    return __uint_as_float(((unsigned)h) << 16) + __uint_as_float(((unsigned)l) << 16);
}

// 3-pass split MFMA: acc += ah*bh + ah*bl + al*bh
#define MFMA3(ACC, AH, AL, BH, BL) { \
    ACC = __builtin_amdgcn_mfma_f32_16x16x32_bf16(AH, BH, ACC, 0, 0, 0); \
    ACC = __builtin_amdgcn_mfma_f32_16x16x32_bf16(AH, BL, ACC, 0, 0, 0); \
    ACC = __builtin_amdgcn_mfma_f32_16x16x32_bf16(AL, BH, ACC, 0, 0, 0); }

// ---- weight transpose + split: src [K][N] f32 (batch z) -> dh/dl [N][K] bf16 ----
__global__ __launch_bounds__(256)
void convert_w(const float* __restrict__ src, u16* __restrict__ dh,
               u16* __restrict__ dl, int K, int N) {
    const int e = blockIdx.z;
    src += (size_t)e * K * N;
    dh  += (size_t)e * K * N;
    dl  += (size_t)e * K * N;
    __shared__ float ts[64][65];
    const int t = threadIdx.x;
    const int k0 = blockIdx.y * 64, n0 = blockIdx.x * 64;
    const int r = t >> 4, c4 = (t & 15) * 4;
    #pragma unroll
    for (int i = 0; i < 4; ++i) {
        const int kr = r + i * 16;
        float4 v = *(const float4*)(src + (size_t)(k0 + kr) * N + n0 + c4);
        ts[kr][c4 + 0] = v.x; ts[kr][c4 + 1] = v.y;
        ts[kr][c4 + 2] = v.z; ts[kr][c4 + 3] = v.w;
    }
    __syncthreads();
    #pragma unroll
    for (int i = 0; i < 4; ++i) {
        const int nr = r + i * 16;
        u16x4 h4, l4;
        #pragma unroll
        for (int j = 0; j < 4; ++j) {
            u16 h, l; bf16_split(ts[c4 + j][nr], h, l);
            h4[j] = h; l4[j] = l;
        }
        *(u16x4*)(dh + (size_t)(n0 + nr) * K + k0 + c4) = h4;
        *(u16x4*)(dl + (size_t)(n0 + nr) * K + k0 + c4) = l4;
    }
}

// ---- LayerNorm -> bf16 hi/lo planes ----
__global__ __launch_bounds__(256)
void ln_kernel(const float* __restrict__ x, const float* __restrict__ sc,
               const float* __restrict__ bi, u16* __restrict__ yh,
               u16* __restrict__ yl) {
    const int row = blockIdx.x;
    const int t = threadIdx.x;
    const float* xr = x + (size_t)row * DM;
    float4 v = *(const float4*)(xr + t * 4);
    float s  = v.x + v.y + v.z + v.w;
    float s2 = v.x*v.x + v.y*v.y + v.z*v.z + v.w*v.w;
    #pragma unroll
    for (int off = 32; off; off >>= 1) {
        s  += __shfl_down(s, off);
        s2 += __shfl_down(s2, off);
    }
    __shared__ float ss[4], ss2[4];
    const int wid = t >> 6;
    if ((t & 63) == 0) { ss[wid] = s; ss2[wid] = s2; }
    __syncthreads();
    const float tot  = ss[0] + ss[1] + ss[2] + ss[3];
    const float tot2 = ss2[0] + ss2[1] + ss2[2] + ss2[3];
    const float mu  = tot * (1.0f / DM);
    const float var = tot2 * (1.0f / DM) - mu * mu;
    const float rcp = rsqrtf(var + LN_EPS);
    float4 sv = *(const float4*)(sc + t * 4);
    float4 bv = *(const float4*)(bi + t * 4);
    float o[4];
    o[0] = (v.x - mu) * rcp * sv.x + bv.x;
    o[1] = (v.y - mu) * rcp * sv.y + bv.y;
    o[2] = (v.z - mu) * rcp * sv.z + bv.z;
    o[3] = (v.w - mu) * rcp * sv.w + bv.w;
    u16x4 h4, l4;
    #pragma unroll
    for (int j = 0; j < 4; ++j) { u16 h, l; bf16_split(o[j], h, l); h4[j] = h; l4[j] = l; }
    *(u16x4*)(yh + (size_t)row * DM + t * 4) = h4;
    *(u16x4*)(yl + (size_t)row * DM + t * 4) = l4;
}

// ---- QKV GEMM 128x128x32: planes out [b,h,s,d] hi/lo for q,k,v ----
__global__ __launch_bounds__(256, 2)
void qkv_gemm(const u16* __restrict__ Ah, const u16* __restrict__ Al,
              const u16* __restrict__ Bh, const u16* __restrict__ Bl,
              const float* __restrict__ bias,
              u16* __restrict__ qh, u16* __restrict__ ql,
              u16* __restrict__ kh, u16* __restrict__ kl,
              u16* __restrict__ vh, u16* __restrict__ vl) {
    __shared__ __align__(16) u16 Ahs[128 * 32], Als[128 * 32];
    __shared__ __align__(16) u16 Bhs[128 * 32], Bls[128 * 32];
    int bx = blockIdx.x, by = blockIdx.y;
    xcd_swz(bx, by);
    const int t = threadIdx.x;
    const int m0 = by * 128, n0 = bx * 128;
    const int lane = t & 63, wid = t >> 6;
    const int wm = wid >> 1, wn = wid & 1;
    const int lr = lane & 15, lc = lane >> 4;
    const int srow = lane >> 2, skk = (lane & 3) * 8;
    const int w32 = wid * 32;
    const u16* Agh = Ah + (size_t)(m0 + w32 + srow) * KDIM + skk;
    const u16* Agl = Al + (size_t)(m0 + w32 + srow) * KDIM + skk;
    const u16* Bgh = Bh + (size_t)(n0 + w32 + srow) * KDIM + skk;
    const u16* Bgl = Bl + (size_t)(n0 + w32 + srow) * KDIM + skk;

    f32x4 acc[4][4];
    #pragma unroll
    for (int i = 0; i < 4; ++i)
        #pragma unroll
        for (int j = 0; j < 4; ++j)
            #pragma unroll
            for (int r = 0; r < 4; ++r) acc[i][j][r] = 0.0f;

    for (int kt = 0; kt < NT; ++kt) {
        const int ko = kt * 32;
        gll16(Agh + ko,              &Ahs[w32 * 32]);
        gll16(Agh + ko + 16 * KDIM,  &Ahs[(w32 + 16) * 32]);
        gll16(Agl + ko,              &Als[w32 * 32]);
        gll16(Agl + ko + 16 * KDIM,  &Als[(w32 + 16) * 32]);
        gll16(Bgh + ko,              &Bhs[w32 * 32]);
        gll16(Bgh + ko + 16 * KDIM,  &Bhs[(w32 + 16) * 32]);
        gll16(Bgl + ko,              &Bls[w32 * 32]);
        gll16(Bgl + ko + 16 * KDIM,  &Bls[(w32 + 16) * 32]);
        __syncthreads();
        s16x8 fa_h[4], fa_l[4], fb_h[4], fb_l[4];
        #pragma unroll
        for (int fi = 0; fi < 4; ++fi) {
            const int ro = (wm * 64 + fi * 16 + lr) * 32 + lc * 8;
            fa_h[fi] = *(const s16x8*)&Ahs[ro];
            fa_l[fi] = *(const s16x8*)&Als[ro];
        }
        #pragma unroll
        for (int fj = 0; fj < 4; ++fj) {
            const int ro = (wn * 64 + fj * 16 + lr) * 32 + lc * 8;
            fb_h[fj] = *(const s16x8*)&Bhs[ro];
            fb_l[fj] = *(const s16x8*)&Bls[ro];
        }
        #pragma unroll
        for (int fi = 0; fi < 4; ++fi)
            #pragma unroll
            for (int fj = 0; fj < 4; ++fj)
                MFMA3(acc[fi][fj], fa_h[fi], fa_l[fi], fb_h[fj], fb_l[fj])
        __syncthreads();
    }

    #pragma unroll
    for (int fj = 0; fj < 4; ++fj) {
        const int col = n0 + wn * 64 + fj * 16 + lr;
        const int sec = col >> 10;              // 0=q 1=k 2=v
        const int hh = (col & 1023) >> 6;
        const int dd = col & 63;
        const float bv = bias[col];
        u16* ph = (sec == 0) ? qh : (sec == 1) ? kh : vh;
        u16* pl = (sec == 0) ? ql : (sec == 1) ? kl : vl;
        #pragma unroll
        for (int fi = 0; fi < 4; ++fi)
            #pragma unroll
            for (int r = 0; r < 4; ++r) {
                const int row = m0 + wm * 64 + fi * 16 + lc * 4 + r;
                const int b = row >> 11, s = row & 2047;
                const size_t idx = ((size_t)(b * 16 + hh) * 2048 + s) * 64 + dd;
                u16 h, l; bf16_split(acc[fi][fj][r] + bv, h, l);
                ph[idx] = h; pl[idx] = l;
            }
    }
}

// ---- MFMA GEMM 128x128x32, gll staging. A [M][K] planes, B [N][K] planes ----
// MODE 0: C(f32) = A@B^T + bias + res ; MODE 1: Cb(bf16) = A@B^T + bias
template<int MODE>
__global__ __launch_bounds__(256, 2)
void gemm_mfma(const u16* __restrict__ Ah, const u16* __restrict__ Al,
               const u16* __restrict__ Bh, const u16* __restrict__ Bl,
               const float* __restrict__ bias, const float* __restrict__ res,
               float* __restrict__ C, u16* __restrict__ Cb, int N) {
    __shared__ __align__(16) u16 Ahs[128 * 32], Als[128 * 32];
    __shared__ __align__(16) u16 Bhs[128 * 32], Bls[128 * 32];
    int bx = blockIdx.x, by = blockIdx.y;
    xcd_swz(bx, by);
    const int t = threadIdx.x;
    const int m0 = by * 128, n0 = bx * 128;
    const int lane = t & 63, wid = t >> 6;
    const int wm = wid >> 1, wn = wid & 1;
    const int lr = lane & 15, lc = lane >> 4;
    const int srow = lane >> 2, skk = (lane & 3) * 8;
    const int w32 = wid * 32;
    const u16* Agh = Ah + (size_t)(m0 + w32 + srow) * KDIM + skk;
    const u16* Agl = Al + (size_t)(m0 + w32 + srow) * KDIM + skk;
    const u16* Bgh = Bh + (size_t)(n0 + w32 + srow) * KDIM + skk;
    const u16* Bgl = Bl + (size_t)(n0 + w32 + srow) * KDIM + skk;

    f32x4 acc[4][4];
    #pragma unroll
    for (int i = 0; i < 4; ++i)
        #pragma unroll
        for (int j = 0; j < 4; ++j)
            #pragma unroll
            for (int r = 0; r < 4; ++r) acc[i][j][r] = 0.0f;

    for (int kt = 0; kt < NT; ++kt) {
        const int ko = kt * 32;
        gll16(Agh + ko,              &Ahs[w32 * 32]);
        gll16(Agh + ko + 16 * KDIM,  &Ahs[(w32 + 16) * 32]);
        gll16(Agl + ko,              &Als[w32 * 32]);
        gll16(Agl + ko + 16 * KDIM,  &Als[(w32 + 16) * 32]);
        gll16(Bgh + ko,              &Bhs[w32 * 32]);
        gll16(Bgh + ko + 16 * KDIM,  &Bhs[(w32 + 16) * 32]);
        gll16(Bgl + ko,              &Bls[w32 * 32]);
        gll16(Bgl + ko + 16 * KDIM,  &Bls[(w32 + 16) * 32]);
        __syncthreads();
        s16x8 fa_h[4], fa_l[4], fb_h[4], fb_l[4];
        #pragma unroll
        for (int fi = 0; fi < 4; ++fi) {
            const int ro = (wm * 64 + fi * 16 + lr) * 32 + lc * 8;
            fa_h[fi] = *(const s16x8*)&Ahs[ro];
            fa_l[fi] = *(const s16x8*)&Als[ro];
        }
        #pragma unroll
        for (int fj = 0; fj < 4; ++fj) {
            const int ro = (wn * 64 + fj * 16 + lr) * 32 + lc * 8;
            fb_h[fj] = *(const s16x8*)&Bhs[ro];
            fb_l[fj] = *(const s16x8*)&Bls[ro];
        }
        #pragma unroll
        for (int fi = 0; fi < 4; ++fi)
            #pragma unroll
            for (int fj = 0; fj < 4; ++fj)
                MFMA3(acc[fi][fj], fa_h[fi], fa_l[fi], fb_h[fj], fb_l[fj])
        __syncthreads();
    }

    #pragma unroll
    for (int fj = 0; fj < 4; ++fj) {
        const int col = n0 + wn * 64 + fj * 16 + lr;
        const float bv = bias[col];
        #pragma unroll
        for (int fi = 0; fi < 4; ++fi)
            #pragma unroll
            for (int r = 0; r < 4; ++r) {
                const int row = m0 + wm * 64 + fi * 16 + lc * 4 + r;
                if (MODE == 0) {
                    C[(size_t)row * N + col] =
                        acc[fi][fj][r] + bv + res[(size_t)row * N + col];
                } else {
                    Cb[(size_t)row * N + col] = f2bf(acc[fi][fj][r] + bv);
                }
            }
    }
}

// ---- combine: comb[t,f] = sum_e r[t,e] * eo[t, e*1024+f] -> hi/lo planes ----
__global__ __launch_bounds__(256)
void combine_kernel(const u16* __restrict__ eo, const float* __restrict__ r,
                    u16* __restrict__ ch, u16* __restrict__ cl) {
    const int t = blockIdx.x;
    const int f0 = threadIdx.x * 4;
    const float* rt = r + (size_t)t * 8;
    float rr[8];
    #pragma unroll
    for (int e = 0; e < 8; ++e) rr[e] = rt[e];
    const u16* row = eo + (size_t)t * 8192;
    float acc[4] = {0.0f, 0.0f, 0.0f, 0.0f};
    #pragma unroll
    for (int e = 0; e < 8; ++e) {
        u16x4 v = *(const u16x4*)(row + e * 1024 + f0);
        #pragma unroll
        for (int j = 0; j < 4; ++j)
            acc[j] += rr[e] * __uint_as_float(((unsigned)v[j]) << 16);
    }
    u16x4 h4, l4;
    #pragma unroll
    for (int j = 0; j < 4; ++j) { u16 h, l; bf16_split(acc[j], h, l); h4[j] = h; l4[j] = l; }
    *(u16x4*)(ch + (size_t)t * 1024 + f0) = h4;
    *(u16x4*)(cl + (size_t)t * 1024 + f0) = l4;
}

// ---- MFMA flash attention: bf16 hi/lo, online softmax, 4 waves x 16 q-rows ----
// T14 async-STAGE: next tile's K/V global loads issued into regs during compute.
// K_lds [64 rows][64 d] XOR-swizzled (byte ^= (row&7)<<4); Vt_lds [64 d][72 k];
// P_lds per-wave [16 q][72 k].
#define VTS 72
__global__ __launch_bounds__(256, 3)
void attn_kernel(const u16* __restrict__ qh, const u16* __restrict__ ql,
                 const u16* __restrict__ kh, const u16* __restrict__ kl,
                 const u16* __restrict__ vh, const u16* __restrict__ vl,
                 u16* __restrict__ oh, u16* __restrict__ ol) {
    __shared__ __align__(16) u16 Khs[64 * 64], Kls[64 * 64];
    __shared__ __align__(16) u16 Vth[64 * VTS], Vtl[64 * VTS];
    __shared__ __align__(16) u16 Phs[4 * 16 * VTS], Pls[4 * 16 * VTS];
    const int t = threadIdx.x;
    const int lane = t & 63, w = t >> 6;
    const int lr = lane & 15, lc = lane >> 4;
    const int q0 = blockIdx.x * 64;
    const int bh = blockIdx.y;
    const int b = bh >> 4, h = bh & 15;
    const size_t head = (size_t)bh * 2048 * 64;

    // Q fragments (A-frag: row = lr, d = c*32 + lc*8), rows q0 + w*16 + lr
    s16x8 qf_h[2], qf_l[2];
    {
        const size_t qrow = head + (size_t)(q0 + w * 16 + lr) * 64;
        #pragma unroll
        for (int c = 0; c < 2; ++c) {
            qf_h[c] = *(const s16x8*)(qh + qrow + c * 32 + lc * 8);
            qf_l[c] = *(const s16x8*)(ql + qrow + c * 32 + lc * 8);
        }
    }

    f32x4 o4[4];
    #pragma unroll
    for (int dt = 0; dt < 4; ++dt)
        #pragma unroll
        for (int r = 0; r < 4; ++r) o4[dt][r] = 0.0f;
    float m_run[4], l_run[4];
    #pragma unroll
    for (int r = 0; r < 4; ++r) { m_run[r] = -3.0e38f; l_run[r] = 0.0f; }

    char* const kbase_h = (char*)Khs;
    char* const kbase_l = (char*)Kls;
    u16* const pmy_h = Phs + w * 16 * VTS;
    u16* const pmy_l = Pls + w * 16 * VTS;

    // staging role: wave -> plane (w>>1) and d-half (w&1)
    const int dbase = (w & 1) * 32;
    const u16* kplane = (w >> 1) ? kl : kh;
    const u16* vplane = (w >> 1) ? vl : vh;
    char* const kdst = (w >> 1) ? kbase_l : kbase_h;
    u16* const vdst = (w >> 1) ? Vtl : Vth;

    u16x8 kreg[4], vreg[4];
    // prologue: load tile 0 into regs
    {
        const size_t grow = head + (size_t)(0 * 64 + lane) * 64 + dbase;
        #pragma unroll
        for (int jj = 0; jj < 4; ++jj) {
            kreg[jj] = *(const u16x8*)(kplane + grow + jj * 8);
            vreg[jj] = *(const u16x8*)(vplane + grow + jj * 8);
        }
    }

    for (int kt = 0; kt < 32; ++kt) {
        __syncthreads();  // previous tile fully consumed by all waves
        // ---- write staged regs to LDS (K swizzled, V transposed) ----
        #pragma unroll
        for (int jj = 0; jj < 4; ++jj) {
            const int off = (lane * 128 + dbase * 2 + jj * 16) ^ ((lane & 7) << 4);
            *(u16x8*)(kdst + off) = kreg[jj];
            #pragma unroll
            for (int i = 0; i < 8; ++i)
                vdst[(dbase + jj * 8 + i) * VTS + lane] = vreg[jj][i];
        }
        // ---- issue next tile's global loads (latency hides under compute) ----
        if (kt + 1 < 32) {
            const size_t grow = head + (size_t)((kt + 1) * 64 + lane) * 64 + dbase;
            #pragma unroll
            for (int jj = 0; jj < 4; ++jj) {
                kreg[jj] = *(const u16x8*)(kplane + grow + jj * 8);
                vreg[jj] = *(const u16x8*)(vplane + grow + jj * 8);
            }
        }
        __syncthreads();  // this tile's LDS ready

        // ---- S = Q K^T (3-pass), tiles j: k = j*16 + lr ----
        f32x4 s4[4];
        const int kxor = (lr & 7) << 4;
        #pragma unroll
        for (int j = 0; j < 4; ++j) {
            #pragma unroll
            for (int r = 0; r < 4; ++r) s4[j][r] = 0.0f;
            #pragma unroll
            for (int c = 0; c < 2; ++c) {
                const int off = ((j * 16 + lr) * 128 + c * 64 + lc * 16) ^ kxor;
                s16x8 kb_h = *(const s16x8*)(kbase_h + off);
                s16x8 kb_l = *(const s16x8*)(kbase_l + off);
                MFMA3(s4[j], qf_h[c], qf_l[c], kb_h, kb_l)
            }
        }
        // ---- online softmax (rows q = lc*4 + r; reduce over lr-group) ----
        #pragma unroll
        for (int j = 0; j < 4; ++j)
            #pragma unroll
            for (int r = 0; r < 4; ++r) s4[j][r] *= 0.125f;
        #pragma unroll
        for (int r = 0; r < 4; ++r) {
            float tm = fmaxf(fmaxf(s4[0][r], s4[1][r]), fmaxf(s4[2][r], s4[3][r]));
            tm = fmaxf(tm, __shfl_xor(tm, 1));
            tm = fmaxf(tm, __shfl_xor(tm, 2));
            tm = fmaxf(tm, __shfl_xor(tm, 4));
            tm = fmaxf(tm, __shfl_xor(tm, 8));
            const float mn = fmaxf(m_run[r], tm);
            const float corr = __expf(m_run[r] - mn);
            m_run[r] = mn;
            float ps = 0.0f;
            #pragma unroll
            for (int j = 0; j < 4; ++j) {
                const float p = __expf(s4[j][r] - mn);
                s4[j][r] = p;
                ps += p;
            }
            ps += __shfl_xor(ps, 1);
            ps += __shfl_xor(ps, 2);
            ps += __shfl_xor(ps, 4);
            ps += __shfl_xor(ps, 8);
            l_run[r] = l_run[r] * corr + ps;
            #pragma unroll
            for (int dt = 0; dt < 4; ++dt) o4[dt][r] *= corr;
        }
        // ---- write P hi/lo to per-wave LDS [q][VTS] ----
        #pragma unroll
        for (int j = 0; j < 4; ++j)
            #pragma unroll
            for (int r = 0; r < 4; ++r) {
                u16 ph, pl; bf16_split(s4[j][r], ph, pl);
                const int pidx = (lc * 4 + r) * VTS + j * 16 + lr;
                pmy_h[pidx] = ph;
                pmy_l[pidx] = pl;
            }
        // ---- O += P V (3-pass): A = P rows q=lr, B = Vt cols d ----
        #pragma unroll
        for (int kc = 0; kc < 2; ++kc) {
            const int pbase = lr * VTS + kc * 32 + lc * 8;
            s16x8 pa_h = *(const s16x8*)(pmy_h + pbase);
            s16x8 pa_l = *(const s16x8*)(pmy_l + pbase);
            #pragma unroll
            for (int dt = 0; dt < 4; ++dt) {
                const int vbase = (dt * 16 + lr) * VTS + kc * 32 + lc * 8;
                s16x8 vb_h = *(const s16x8*)(Vth + vbase);
                s16x8 vb_l = *(const s16x8*)(Vtl + vbase);
                MFMA3(o4[dt], pa_h, pa_l, vb_h, vb_l)
            }
        }
    }

    // ---- epilogue: normalize, split, store (rows q = lc*4+r, cols d = dt*16+lr) ----
    float inv[4];
    #pragma unroll
    for (int r = 0; r < 4; ++r) inv[r] = 1.0f / l_run[r];
    #pragma unroll
    for (int dt = 0; dt < 4; ++dt)
        #pragma unroll
        for (int r = 0; r < 4; ++r) {
            const int tok = b * 2048 + q0 + w * 16 + lc * 4 + r;
            const size_t idx = (size_t)tok * 1024 + h * 64 + dt * 16 + lr;
            u16 hh, ll; bf16_split(o4[dt][r] * inv[r], hh, ll);
            oh[idx] = hh; ol[idx] = ll;
        }
}

// ---- router: logits + softmax over 8 experts (reads y planes) ----
__global__ __launch_bounds__(64)
void router_kernel(const u16* __restrict__ yh, const u16* __restrict__ yl,
                   const float* __restrict__ rw, float* __restrict__ r) {
    const int tok = blockIdx.x;
    const int lane = threadIdx.x;
    const u16* yhr = yh + (size_t)tok * DM;
    const u16* ylr = yl + (size_t)tok * DM;
    float acc[8] = {0, 0, 0, 0, 0, 0, 0, 0};
    #pragma unroll
    for (int i = 0; i < 16; ++i) {
        const int hh = i * 64 + lane;
        const float yv = bf16_comb(yhr[hh], ylr[hh]);
        const float4 w0 = *(const float4*)(rw + hh * 8);
        const float4 w1 = *(const float4*)(rw + hh * 8 + 4);
        acc[0] = fmaf(yv, w0.x, acc[0]); acc[1] = fmaf(yv, w0.y, acc[1]);
        acc[2] = fmaf(yv, w0.z, acc[2]); acc[3] = fmaf(yv, w0.w, acc[3]);
        acc[4] = fmaf(yv, w1.x, acc[4]); acc[5] = fmaf(yv, w1.y, acc[5]);
        acc[6] = fmaf(yv, w1.z, acc[6]); acc[7] = fmaf(yv, w1.w, acc[7]);
    }
    #pragma unroll
    for (int off = 32; off; off >>= 1)
        #pragma unroll
        for (int e = 0; e < 8; ++e) acc[e] += __shfl_down(acc[e], off);
    if (lane == 0) {
        float mx = acc[0];
        #pragma unroll
        for (int e = 1; e < 8; ++e) mx = fmaxf(mx, acc[e]);
        float p[8], sum = 0.0f;
        #pragma unroll
        for (int e = 0; e < 8; ++e) { p[e] = __expf(acc[e] - mx); sum += p[e]; }
        const float inv = 1.0f / sum;
        #pragma unroll
        for (int e = 0; e < 8; ++e) r[(size_t)tok * 8 + e] = p[e] * inv;
    }
}

// ---------------- launch ----------------
extern "C" void kernel_launch(void* const* d_in, const int* in_sizes, int n_in,
                              void* d_out, int out_size, void* d_ws, size_t ws_size,
                              hipStream_t stream) {
    const float* x    = (const float*)d_in[0];
    const float* ln1s = (const float*)d_in[1];
    const float* ln1b = (const float*)d_in[2];
    const float* Wqkv = (const float*)d_in[3];
    const float* bqkv = (const float*)d_in[4];
    const float* Wo   = (const float*)d_in[5];
    const float* bo   = (const float*)d_in[6];
    const float* ln2s = (const float*)d_in[7];
    const float* ln2b = (const float*)d_in[8];
    const float* rW   = (const float*)d_in[9];
    const float* We   = (const float*)d_in[10];
    const float* be   = (const float*)d_in[11];
    const float* Wmo  = (const float*)d_in[12];
    const float* bmo  = (const float*)d_in[13];
    float* out = (float*)d_out;

    char* w = (char*)d_ws;
    auto carve = [&](size_t bytes) {
        void* p = (void*)w;
        w += (bytes + 255) & ~(size_t)255;
        return p;
    };
    const size_t PL = (size_t)T_TOK * DM;  // 4M elements per plane
    // 8 contiguous bf16 planes (64 MiB) -> reused as eo [4096][8192] bf16
    u16* qh = (u16*)carve(PL * 2); u16* ql = (u16*)carve(PL * 2);
    u16* kh = (u16*)carve(PL * 2); u16* kl = (u16*)carve(PL * 2);
    u16* vh = (u16*)carve(PL * 2); u16* vl = (u16*)carve(PL * 2);
    u16* ob_h = (u16*)carve(PL * 2); u16* ob_l = (u16*)carve(PL * 2);
    float* x1  = (float*)carve(PL * 4);
    u16* y_h  = (u16*)carve(PL * 2); u16* y_l  = (u16*)carve(PL * 2);
    float* r  = (float*)carve((size_t)T_TOK * 8 * 4);
    u16* Wqkv_h = (u16*)carve((size_t)DM * NQKV * 2);
    u16* Wqkv_l = (u16*)carve((size_t)DM * NQKV * 2);
    u16* Wo_h   = (u16*)carve((size_t)DM * DM * 2);
    u16* Wo_l   = (u16*)carve((size_t)DM * DM * 2);
    u16* We_h   = (u16*)carve((size_t)8 * DM * DM * 2);
    u16* We_l   = (u16*)carve((size_t)8 * DM * DM * 2);
    u16* Wmo_h  = (u16*)carve((size_t)DM * DM * 2);
    u16* Wmo_l  = (u16*)carve((size_t)DM * DM * 2);
    // eo aliases the 8 dead q/k/v/ob planes (exactly 64 MiB)
    u16* eo = qh;
    // comb planes alias dead y planes
    u16* cb_h = y_h;
    u16* cb_l = y_l;

    // ---- weight transpose+split ----
    convert_w<<<dim3(NQKV / 64, DM / 64, 1), 256, 0, stream>>>(Wqkv, Wqkv_h, Wqkv_l, DM, NQKV);
    convert_w<<<dim3(DM / 64, DM / 64, 1), 256, 0, stream>>>(Wo, Wo_h, Wo_l, DM, DM);
    convert_w<<<dim3(DM / 64, DM / 64, 8), 256, 0, stream>>>(We, We_h, We_l, DM, DM);
    convert_w<<<dim3(DM / 64, DM / 64, 1), 256, 0, stream>>>(Wmo, Wmo_h, Wmo_l, DM, DM);

    // 1. y = LN1(x) -> planes
    ln_kernel<<<T_TOK, 256, 0, stream>>>(x, ln1s, ln1b, y_h, y_l);
    // 2. q/k/v planes = split(y @ Wqkv + bqkv) in [b,h,s,d]
    qkv_gemm<<<dim3(NQKV / 128, T_TOK / 128), 256, 0, stream>>>(
        y_h, y_l, Wqkv_h, Wqkv_l, bqkv, qh, ql, kh, kl, vh, vl);
    // 3. ob = attention(q,k,v) -> planes
    attn_kernel<<<dim3(32, 32), 256, 0, stream>>>(qh, ql, kh, kl, vh, vl, ob_h, ob_l);
    // 4. x1 = x + ob @ Wo + bo
    gemm_mfma<0><<<dim3(DM / 128, T_TOK / 128), 256, 0, stream>>>(
        ob_h, ob_l, Wo_h, Wo_l, bo, x, x1, nullptr, DM);
    // 5. y = LN2(x1) -> planes
    ln_kernel<<<T_TOK, 256, 0, stream>>>(x1, ln2s, ln2b, y_h, y_l);
    // 6. r = softmax(y @ rW)
    router_kernel<<<T_TOK, 64, 0, stream>>>(y_h, y_l, rW, r);
    // 7. eo = bf16(y @ We_all + be)  [4096 x 8192]
    gemm_mfma<1><<<dim3(8192 / 128, T_TOK / 128), 256, 0, stream>>>(
        y_h, y_l, We_h, We_l, be, nullptr, nullptr, eo, 8192);
    // 8. comb = sum_e r_e * eo_e -> planes (alias y)
    combine_kernel<<<T_TOK, 256, 0, stream>>>(eo, r, cb_h, cb_l);
    // 9. out = x1 + comb @ Wmo + bmo
    gemm_mfma<0><<<dim3(DM / 128, T_TOK / 128), 256, 0, stream>>>(
        cb_h, cb_l, Wmo_h, Wmo_l, bmo, x1, out, nullptr, DM);
}

// Round 10
// 764.047 us; speedup vs baseline: 3.9936x; 1.0794x over previous
//
#include <hip/hip_runtime.h>
#include <hip/hip_bf16.h>

typedef unsigned short u16;
typedef float f32x4 __attribute__((ext_vector_type(4)));
typedef short s16x8 __attribute__((ext_vector_type(8)));
typedef unsigned short u16x4 __attribute__((ext_vector_type(4)));
typedef unsigned short u16x8 __attribute__((ext_vector_type(8)));

#define T_TOK 4096
#define DM 1024
#define NQKV 3072
#define LN_EPS 1e-6f
#define KDIM 1024
#define NT 32   // KDIM / 32 (qkv_gemm)
#define NT2 16  // KDIM / 64 (gemm_mfma BK=64)

// ---- async global->LDS, 16B per lane. LDS dest = uniform base + lane*16. ----
__device__ __forceinline__ void gll16(const void* g, void* l) {
    __builtin_amdgcn_global_load_lds(
        (const __attribute__((address_space(1))) void*)g,
        (__attribute__((address_space(3))) void*)l, 16, 0, 0);
}

// ---- XCD-aware block swizzle (requires gx*gy % 8 == 0; all our grids comply) ----
__device__ __forceinline__ void xcd_swz(int& bx, int& by) {
    const int gx = gridDim.x, gy = gridDim.y;
    const int nwg = gx * gy;
    const int lin = by * gx + bx;
    const int cpx = nwg >> 3;
    const int swz = (lin & 7) * cpx + (lin >> 3);
    bx = swz % gx;
    by = swz / gx;
}

// ---- bf16 split: x ~= hi + lo, each RNE bf16. |err| <= ~2^-17 |x| ----
__device__ __forceinline__ void bf16_split(float x, u16& hi, u16& lo) {
    unsigned xb = __float_as_uint(x);
    unsigned rh = xb + 0x7fffu + ((xb >> 16) & 1u);
    hi = (u16)(rh >> 16);
    float hf = __uint_as_float(((unsigned)hi) << 16);
    float rs = x - hf;
    unsigned rb = __float_as_uint(rs);
    unsigned rl = rb + 0x7fffu + ((rb >> 16) & 1u);
    lo = (u16)(rl >> 16);
}
__device__ __forceinline__ u16 f2bf(float x) {  // RNE to single bf16
    unsigned xb = __float_as_uint(x);
    return (u16)((xb + 0x7fffu + ((xb >> 16) & 1u)) >> 16);
}
__device__ __forceinline__ float bf16_comb(u16 h, u16 l) {
    return __uint_as_float(((unsigned)h) << 16) + __uint_as_float(((unsigned)l) << 16);
}

// 3-pass split MFMA: acc += ah*bh + ah*bl + al*bh
#define MFMA3(ACC, AH, AL, BH, BL) { \
    ACC = __builtin_amdgcn_mfma_f32_16x16x32_bf16(AH, BH, ACC, 0, 0, 0); \
    ACC = __builtin_amdgcn_mfma_f32_16x16x32_bf16(AH, BL, ACC, 0, 0, 0); \
    ACC = __builtin_amdgcn_mfma_f32_16x16x32_bf16(AL, BH, ACC, 0, 0, 0); }

// ---- weight transpose + split: src [K][N] f32 (batch z) -> dh/dl [N][K] bf16 ----
__global__ __launch_bounds__(256)
void convert_w(const float* __restrict__ src, u16* __restrict__ dh,
               u16* __restrict__ dl, int K, int N) {
    const int e = blockIdx.z;
    src += (size_t)e * K * N;
    dh  += (size_t)e * K * N;
    dl  += (size_t)e * K * N;
    __shared__ float ts[64][65];
    const int t = threadIdx.x;
    const int k0 = blockIdx.y * 64, n0 = blockIdx.x * 64;
    const int r = t >> 4, c4 = (t & 15) * 4;
    #pragma unroll
    for (int i = 0; i < 4; ++i) {
        const int kr = r + i * 16;
        float4 v = *(const float4*)(src + (size_t)(k0 + kr) * N + n0 + c4);
        ts[kr][c4 + 0] = v.x; ts[kr][c4 + 1] = v.y;
        ts[kr][c4 + 2] = v.z; ts[kr][c4 + 3] = v.w;
    }
    __syncthreads();
    #pragma unroll
    for (int i = 0; i < 4; ++i) {
        const int nr = r + i * 16;
        u16x4 h4, l4;
        #pragma unroll
        for (int j = 0; j < 4; ++j) {
            u16 h, l; bf16_split(ts[c4 + j][nr], h, l);
            h4[j] = h; l4[j] = l;
        }
        *(u16x4*)(dh + (size_t)(n0 + nr) * K + k0 + c4) = h4;
        *(u16x4*)(dl + (size_t)(n0 + nr) * K + k0 + c4) = l4;
    }
}

// ---- LayerNorm -> bf16 hi/lo planes ----
__global__ __launch_bounds__(256)
void ln_kernel(const float* __restrict__ x, const float* __restrict__ sc,
               const float* __restrict__ bi, u16* __restrict__ yh,
               u16* __restrict__ yl) {
    const int row = blockIdx.x;
    const int t = threadIdx.x;
    const float* xr = x + (size_t)row * DM;
    float4 v = *(const float4*)(xr + t * 4);
    float s  = v.x + v.y + v.z + v.w;
    float s2 = v.x*v.x + v.y*v.y + v.z*v.z + v.w*v.w;
    #pragma unroll
    for (int off = 32; off; off >>= 1) {
        s  += __shfl_down(s, off);
        s2 += __shfl_down(s2, off);
    }
    __shared__ float ss[4], ss2[4];
    const int wid = t >> 6;
    if ((t & 63) == 0) { ss[wid] = s; ss2[wid] = s2; }
    __syncthreads();
    const float tot  = ss[0] + ss[1] + ss[2] + ss[3];
    const float tot2 = ss2[0] + ss2[1] + ss2[2] + ss2[3];
    const float mu  = tot * (1.0f / DM);
    const float var = tot2 * (1.0f / DM) - mu * mu;
    const float rcp = rsqrtf(var + LN_EPS);
    float4 sv = *(const float4*)(sc + t * 4);
    float4 bv = *(const float4*)(bi + t * 4);
    float o[4];
    o[0] = (v.x - mu) * rcp * sv.x + bv.x;
    o[1] = (v.y - mu) * rcp * sv.y + bv.y;
    o[2] = (v.z - mu) * rcp * sv.z + bv.z;
    o[3] = (v.w - mu) * rcp * sv.w + bv.w;
    u16x4 h4, l4;
    #pragma unroll
    for (int j = 0; j < 4; ++j) { u16 h, l; bf16_split(o[j], h, l); h4[j] = h; l4[j] = l; }
    *(u16x4*)(yh + (size_t)row * DM + t * 4) = h4;
    *(u16x4*)(yl + (size_t)row * DM + t * 4) = l4;
}

// ---- QKV GEMM 128x128x32 (BK=32, unchanged: serves as A/B control) ----
__global__ __launch_bounds__(256, 2)
void qkv_gemm(const u16* __restrict__ Ah, const u16* __restrict__ Al,
              const u16* __restrict__ Bh, const u16* __restrict__ Bl,
              const float* __restrict__ bias,
              u16* __restrict__ qh, u16* __restrict__ ql,
              u16* __restrict__ kh, u16* __restrict__ kl,
              u16* __restrict__ vh, u16* __restrict__ vl) {
    __shared__ __align__(16) u16 Ahs[128 * 32], Als[128 * 32];
    __shared__ __align__(16) u16 Bhs[128 * 32], Bls[128 * 32];
    int bx = blockIdx.x, by = blockIdx.y;
    xcd_swz(bx, by);
    const int t = threadIdx.x;
    const int m0 = by * 128, n0 = bx * 128;
    const int lane = t & 63, wid = t >> 6;
    const int wm = wid >> 1, wn = wid & 1;
    const int lr = lane & 15, lc = lane >> 4;
    const int srow = lane >> 2, skk = (lane & 3) * 8;
    const int w32 = wid * 32;
    const u16* Agh = Ah + (size_t)(m0 + w32 + srow) * KDIM + skk;
    const u16* Agl = Al + (size_t)(m0 + w32 + srow) * KDIM + skk;
    const u16* Bgh = Bh + (size_t)(n0 + w32 + srow) * KDIM + skk;
    const u16* Bgl = Bl + (size_t)(n0 + w32 + srow) * KDIM + skk;

    f32x4 acc[4][4];
    #pragma unroll
    for (int i = 0; i < 4; ++i)
        #pragma unroll
        for (int j = 0; j < 4; ++j)
            #pragma unroll
            for (int r = 0; r < 4; ++r) acc[i][j][r] = 0.0f;

    for (int kt = 0; kt < NT; ++kt) {
        const int ko = kt * 32;
        gll16(Agh + ko,              &Ahs[w32 * 32]);
        gll16(Agh + ko + 16 * KDIM,  &Ahs[(w32 + 16) * 32]);
        gll16(Agl + ko,              &Als[w32 * 32]);
        gll16(Agl + ko + 16 * KDIM,  &Als[(w32 + 16) * 32]);
        gll16(Bgh + ko,              &Bhs[w32 * 32]);
        gll16(Bgh + ko + 16 * KDIM,  &Bhs[(w32 + 16) * 32]);
        gll16(Bgl + ko,              &Bls[w32 * 32]);
        gll16(Bgl + ko + 16 * KDIM,  &Bls[(w32 + 16) * 32]);
        __syncthreads();
        s16x8 fa_h[4], fa_l[4], fb_h[4], fb_l[4];
        #pragma unroll
        for (int fi = 0; fi < 4; ++fi) {
            const int ro = (wm * 64 + fi * 16 + lr) * 32 + lc * 8;
            fa_h[fi] = *(const s16x8*)&Ahs[ro];
            fa_l[fi] = *(const s16x8*)&Als[ro];
        }
        #pragma unroll
        for (int fj = 0; fj < 4; ++fj) {
            const int ro = (wn * 64 + fj * 16 + lr) * 32 + lc * 8;
            fb_h[fj] = *(const s16x8*)&Bhs[ro];
            fb_l[fj] = *(const s16x8*)&Bls[ro];
        }
        #pragma unroll
        for (int fi = 0; fi < 4; ++fi)
            #pragma unroll
            for (int fj = 0; fj < 4; ++fj)
                MFMA3(acc[fi][fj], fa_h[fi], fa_l[fi], fb_h[fj], fb_l[fj])
        __syncthreads();
    }

    #pragma unroll
    for (int fj = 0; fj < 4; ++fj) {
        const int col = n0 + wn * 64 + fj * 16 + lr;
        const int sec = col >> 10;              // 0=q 1=k 2=v
        const int hh = (col & 1023) >> 6;
        const int dd = col & 63;
        const float bv = bias[col];
        u16* ph = (sec == 0) ? qh : (sec == 1) ? kh : vh;
        u16* pl = (sec == 0) ? ql : (sec == 1) ? kl : vl;
        #pragma unroll
        for (int fi = 0; fi < 4; ++fi)
            #pragma unroll
            for (int r = 0; r < 4; ++r) {
                const int row = m0 + wm * 64 + fi * 16 + lc * 4 + r;
                const int b = row >> 11, s = row & 2047;
                const size_t idx = ((size_t)(b * 16 + hh) * 2048 + s) * 64 + dd;
                u16 h, l; bf16_split(acc[fi][fj][r] + bv, h, l);
                ph[idx] = h; pl[idx] = l;
            }
    }
}

// ---- MFMA GEMM 128x128 BK=64, gll staging with both-sides LDS swizzle ----
// LDS[row][c] = G[row][c ^ (row&7)] (16B chunks); write via pre-swizzled global
// source column, read via chunk ^= row&7. Rows of a frag read spread 8 chunks
// -> all 32 banks -> conflict-free.
// MODE 0: C(f32) = A@B^T + bias + res ; MODE 1: Cb(bf16) = A@B^T + bias
template<int MODE>
__global__ __launch_bounds__(256, 2)
void gemm_mfma(const u16* __restrict__ Ah, const u16* __restrict__ Al,
               const u16* __restrict__ Bh, const u16* __restrict__ Bl,
               const float* __restrict__ bias, const float* __restrict__ res,
               float* __restrict__ C, u16* __restrict__ Cb, int N) {
    __shared__ __align__(16) u16 Ahs[128 * 64], Als[128 * 64];
    __shared__ __align__(16) u16 Bhs[128 * 64], Bls[128 * 64];
    int bx = blockIdx.x, by = blockIdx.y;
    xcd_swz(bx, by);
    const int t = threadIdx.x;
    const int m0 = by * 128, n0 = bx * 128;
    const int lane = t & 63, wid = t >> 6;
    const int wm = wid >> 1, wn = wid & 1;
    const int lr = lane & 15, lc = lane >> 4;
    // staging: 64 lanes x 16B = 8 rows/issue; lane -> row lane>>3, chunk lane&7.
    // source column pre-swizzled so LDS stays linear (rule 21).
    const int srow = lane >> 3;
    const int skk  = ((lane & 7) ^ (lane >> 3)) * 8;
    const int w32 = wid * 32;
    const u16* Agh = Ah + (size_t)(m0 + w32 + srow) * KDIM + skk;
    const u16* Agl = Al + (size_t)(m0 + w32 + srow) * KDIM + skk;
    const u16* Bgh = Bh + (size_t)(n0 + w32 + srow) * KDIM + skk;
    const u16* Bgl = Bl + (size_t)(n0 + w32 + srow) * KDIM + skk;

    f32x4 acc[4][4];
    #pragma unroll
    for (int i = 0; i < 4; ++i)
        #pragma unroll
        for (int j = 0; j < 4; ++j)
            #pragma unroll
            for (int r = 0; r < 4; ++r) acc[i][j][r] = 0.0f;

    for (int kt = 0; kt < NT2; ++kt) {
        const int ko = kt * 64;
        #pragma unroll
        for (int i = 0; i < 4; ++i) {
            const int go = ko + i * 8 * KDIM;
            gll16(Agh + go, &Ahs[(w32 + i * 8) * 64]);
            gll16(Agl + go, &Als[(w32 + i * 8) * 64]);
            gll16(Bgh + go, &Bhs[(w32 + i * 8) * 64]);
            gll16(Bgl + go, &Bls[(w32 + i * 8) * 64]);
        }
        __syncthreads();  // vmcnt(0) drain + barrier
        #pragma unroll
        for (int ks = 0; ks < 2; ++ks) {
            s16x8 fa_h[4], fa_l[4], fb_h[4], fb_l[4];
            #pragma unroll
            for (int fi = 0; fi < 4; ++fi) {
                const int row = wm * 64 + fi * 16 + lr;
                const int ro = row * 64 + (((ks * 4 + lc) ^ (row & 7)) << 3);
                fa_h[fi] = *(const s16x8*)&Ahs[ro];
                fa_l[fi] = *(const s16x8*)&Als[ro];
            }
            #pragma unroll
            for (int fj = 0; fj < 4; ++fj) {
                const int row = wn * 64 + fj * 16 + lr;
                const int ro = row * 64 + (((ks * 4 + lc) ^ (row & 7)) << 3);
                fb_h[fj] = *(const s16x8*)&Bhs[ro];
                fb_l[fj] = *(const s16x8*)&Bls[ro];
            }
            #pragma unroll
            for (int fi = 0; fi < 4; ++fi)
                #pragma unroll
                for (int fj = 0; fj < 4; ++fj)
                    MFMA3(acc[fi][fj], fa_h[fi], fa_l[fi], fb_h[fj], fb_l[fj])
        }
        __syncthreads();  // protect LDS before next stage
    }

    #pragma unroll
    for (int fj = 0; fj < 4; ++fj) {
        const int col = n0 + wn * 64 + fj * 16 + lr;
        const float bv = bias[col];
        #pragma unroll
        for (int fi = 0; fi < 4; ++fi)
            #pragma unroll
            for (int r = 0; r < 4; ++r) {
                const int row = m0 + wm * 64 + fi * 16 + lc * 4 + r;
                if (MODE == 0) {
                    C[(size_t)row * N + col] =
                        acc[fi][fj][r] + bv + res[(size_t)row * N + col];
                } else {
                    Cb[(size_t)row * N + col] = f2bf(acc[fi][fj][r] + bv);
                }
            }
    }
}

// ---- combine: comb[t,f] = sum_e r[t,e] * eo[t, e*1024+f] -> hi/lo planes ----
__global__ __launch_bounds__(256)
void combine_kernel(const u16* __restrict__ eo, const float* __restrict__ r,
                    u16* __restrict__ ch, u16* __restrict__ cl) {
    const int t = blockIdx.x;
    const int f0 = threadIdx.x * 4;
    const float* rt = r + (size_t)t * 8;
    float rr[8];
    #pragma unroll
    for (int e = 0; e < 8; ++e) rr[e] = rt[e];
    const u16* row = eo + (size_t)t * 8192;
    float acc[4] = {0.0f, 0.0f, 0.0f, 0.0f};
    #pragma unroll
    for (int e = 0; e < 8; ++e) {
        u16x4 v = *(const u16x4*)(row + e * 1024 + f0);
        #pragma unroll
        for (int j = 0; j < 4; ++j)
            acc[j] += rr[e] * __uint_as_float(((unsigned)v[j]) << 16);
    }
    u16x4 h4, l4;
    #pragma unroll
    for (int j = 0; j < 4; ++j) { u16 h, l; bf16_split(acc[j], h, l); h4[j] = h; l4[j] = l; }
    *(u16x4*)(ch + (size_t)t * 1024 + f0) = h4;
    *(u16x4*)(cl + (size_t)t * 1024 + f0) = l4;
}

// ---- MFMA flash attention: bf16 hi/lo, online softmax, 4 waves x 16 q-rows ----
// T14 async-STAGE + T13 defer-max (THR=8) + T5 setprio around MFMA clusters.
#define VTS 72
__global__ __launch_bounds__(256, 3)
void attn_kernel(const u16* __restrict__ qh, const u16* __restrict__ ql,
                 const u16* __restrict__ kh, const u16* __restrict__ kl,
                 const u16* __restrict__ vh, const u16* __restrict__ vl,
                 u16* __restrict__ oh, u16* __restrict__ ol) {
    __shared__ __align__(16) u16 Khs[64 * 64], Kls[64 * 64];
    __shared__ __align__(16) u16 Vth[64 * VTS], Vtl[64 * VTS];
    __shared__ __align__(16) u16 Phs[4 * 16 * VTS], Pls[4 * 16 * VTS];
    const int t = threadIdx.x;
    const int lane = t & 63, w = t >> 6;
    const int lr = lane & 15, lc = lane >> 4;
    const int q0 = blockIdx.x * 64;
    const int bh = blockIdx.y;
    const int b = bh >> 4, h = bh & 15;
    const size_t head = (size_t)bh * 2048 * 64;

    s16x8 qf_h[2], qf_l[2];
    {
        const size_t qrow = head + (size_t)(q0 + w * 16 + lr) * 64;
        #pragma unroll
        for (int c = 0; c < 2; ++c) {
            qf_h[c] = *(const s16x8*)(qh + qrow + c * 32 + lc * 8);
            qf_l[c] = *(const s16x8*)(ql + qrow + c * 32 + lc * 8);
        }
    }

    f32x4 o4[4];
    #pragma unroll
    for (int dt = 0; dt < 4; ++dt)
        #pragma unroll
        for (int r = 0; r < 4; ++r) o4[dt][r] = 0.0f;
    float m_run[4], l_run[4];
    #pragma unroll
    for (int r = 0; r < 4; ++r) { m_run[r] = -3.0e38f; l_run[r] = 0.0f; }

    char* const kbase_h = (char*)Khs;
    char* const kbase_l = (char*)Kls;
    u16* const pmy_h = Phs + w * 16 * VTS;
    u16* const pmy_l = Pls + w * 16 * VTS;

    const int dbase = (w & 1) * 32;
    const u16* kplane = (w >> 1) ? kl : kh;
    const u16* vplane = (w >> 1) ? vl : vh;
    char* const kdst = (w >> 1) ? kbase_l : kbase_h;
    u16* const vdst = (w >> 1) ? Vtl : Vth;

    u16x8 kreg[4], vreg[4];
    {
        const size_t grow = head + (size_t)(0 * 64 + lane) * 64 + dbase;
        #pragma unroll
        for (int jj = 0; jj < 4; ++jj) {
            kreg[jj] = *(const u16x8*)(kplane + grow + jj * 8);
            vreg[jj] = *(const u16x8*)(vplane + grow + jj * 8);
        }
    }

    for (int kt = 0; kt < 32; ++kt) {
        __syncthreads();  // previous tile fully consumed
        // ---- write staged regs to LDS (K swizzled, V transposed) ----
        #pragma unroll
        for (int jj = 0; jj < 4; ++jj) {
            const int off = (lane * 128 + dbase * 2 + jj * 16) ^ ((lane & 7) << 4);
            *(u16x8*)(kdst + off) = kreg[jj];
            #pragma unroll
            for (int i = 0; i < 8; ++i)
                vdst[(dbase + jj * 8 + i) * VTS + lane] = vreg[jj][i];
        }
        // ---- issue next tile's global loads (hide under compute) ----
        if (kt + 1 < 32) {
            const size_t grow = head + (size_t)((kt + 1) * 64 + lane) * 64 + dbase;
            #pragma unroll
            for (int jj = 0; jj < 4; ++jj) {
                kreg[jj] = *(const u16x8*)(kplane + grow + jj * 8);
                vreg[jj] = *(const u16x8*)(vplane + grow + jj * 8);
            }
        }
        __syncthreads();  // this tile's LDS ready

        // ---- S = Q K^T (3-pass) ----
        f32x4 s4[4];
        const int kxor = (lr & 7) << 4;
        __builtin_amdgcn_s_setprio(1);
        #pragma unroll
        for (int j = 0; j < 4; ++j) {
            #pragma unroll
            for (int r = 0; r < 4; ++r) s4[j][r] = 0.0f;
            #pragma unroll
            for (int c = 0; c < 2; ++c) {
                const int off = ((j * 16 + lr) * 128 + c * 64 + lc * 16) ^ kxor;
                s16x8 kb_h = *(const s16x8*)(kbase_h + off);
                s16x8 kb_l = *(const s16x8*)(kbase_l + off);
                MFMA3(s4[j], qf_h[c], qf_l[c], kb_h, kb_l)
            }
        }
        __builtin_amdgcn_s_setprio(0);

        // ---- online softmax with defer-max (THR=8) ----
        #pragma unroll
        for (int j = 0; j < 4; ++j)
            #pragma unroll
            for (int r = 0; r < 4; ++r) s4[j][r] *= 0.125f;
        float tmx[4];
        #pragma unroll
        for (int r = 0; r < 4; ++r) {
            float tm = fmaxf(fmaxf(s4[0][r], s4[1][r]), fmaxf(s4[2][r], s4[3][r]));
            tm = fmaxf(tm, __shfl_xor(tm, 1));
            tm = fmaxf(tm, __shfl_xor(tm, 2));
            tm = fmaxf(tm, __shfl_xor(tm, 4));
            tm = fmaxf(tm, __shfl_xor(tm, 8));
            tmx[r] = tm;
        }
        const bool grow_m = (tmx[0] > m_run[0] + 8.0f) || (tmx[1] > m_run[1] + 8.0f) ||
                            (tmx[2] > m_run[2] + 8.0f) || (tmx[3] > m_run[3] + 8.0f);
        if (__any(grow_m)) {
            #pragma unroll
            for (int r = 0; r < 4; ++r) {
                const float mn = fmaxf(m_run[r], tmx[r]);
                const float corr = __expf(m_run[r] - mn);
                m_run[r] = mn;
                l_run[r] *= corr;
                #pragma unroll
                for (int dt = 0; dt < 4; ++dt) o4[dt][r] *= corr;
            }
        }
        #pragma unroll
        for (int r = 0; r < 4; ++r) {
            float ps = 0.0f;
            #pragma unroll
            for (int j = 0; j < 4; ++j) {
                const float p = __expf(s4[j][r] - m_run[r]);
                s4[j][r] = p;
                ps += p;
            }
            ps += __shfl_xor(ps, 1);
            ps += __shfl_xor(ps, 2);
            ps += __shfl_xor(ps, 4);
            ps += __shfl_xor(ps, 8);
            l_run[r] += ps;
        }
        // ---- write P hi/lo to per-wave LDS [q][VTS] ----
        #pragma unroll
        for (int j = 0; j < 4; ++j)
            #pragma unroll
            for (int r = 0; r < 4; ++r) {
                u16 ph, pl; bf16_split(s4[j][r], ph, pl);
                const int pidx = (lc * 4 + r) * VTS + j * 16 + lr;
                pmy_h[pidx] = ph;
                pmy_l[pidx] = pl;
            }
        // ---- O += P V (3-pass) ----
        __builtin_amdgcn_s_setprio(1);
        #pragma unroll
        for (int kc = 0; kc < 2; ++kc) {
            const int pbase = lr * VTS + kc * 32 + lc * 8;
            s16x8 pa_h = *(const s16x8*)(pmy_h + pbase);
            s16x8 pa_l = *(const s16x8*)(pmy_l + pbase);
            #pragma unroll
            for (int dt = 0; dt < 4; ++dt) {
                const int vbase = (dt * 16 + lr) * VTS + kc * 32 + lc * 8;
                s16x8 vb_h = *(const s16x8*)(Vth + vbase);
                s16x8 vb_l = *(const s16x8*)(Vtl + vbase);
                MFMA3(o4[dt], pa_h, pa_l, vb_h, vb_l)
            }
        }
        __builtin_amdgcn_s_setprio(0);
    }

    float inv[4];
    #pragma unroll
    for (int r = 0; r < 4; ++r) inv[r] = 1.0f / l_run[r];
    #pragma unroll
    for (int dt = 0; dt < 4; ++dt)
        #pragma unroll
        for (int r = 0; r < 4; ++r) {
            const int tok = b * 2048 + q0 + w * 16 + lc * 4 + r;
            const size_t idx = (size_t)tok * 1024 + h * 64 + dt * 16 + lr;
            u16 hh, ll; bf16_split(o4[dt][r] * inv[r], hh, ll);
            oh[idx] = hh; ol[idx] = ll;
        }
}

// ---- router: logits + softmax over 8 experts (reads y planes) ----
__global__ __launch_bounds__(64)
void router_kernel(const u16* __restrict__ yh, const u16* __restrict__ yl,
                   const float* __restrict__ rw, float* __restrict__ r) {
    const int tok = blockIdx.x;
    const int lane = threadIdx.x;
    const u16* yhr = yh + (size_t)tok * DM;
    const u16* ylr = yl + (size_t)tok * DM;
    float acc[8] = {0, 0, 0, 0, 0, 0, 0, 0};
    #pragma unroll
    for (int i = 0; i < 16; ++i) {
        const int hh = i * 64 + lane;
        const float yv = bf16_comb(yhr[hh], ylr[hh]);
        const float4 w0 = *(const float4*)(rw + hh * 8);
        const float4 w1 = *(const float4*)(rw + hh * 8 + 4);
        acc[0] = fmaf(yv, w0.x, acc[0]); acc[1] = fmaf(yv, w0.y, acc[1]);
        acc[2] = fmaf(yv, w0.z, acc[2]); acc[3] = fmaf(yv, w0.w, acc[3]);
        acc[4] = fmaf(yv, w1.x, acc[4]); acc[5] = fmaf(yv, w1.y, acc[5]);
        acc[6] = fmaf(yv, w1.z, acc[6]); acc[7] = fmaf(yv, w1.w, acc[7]);
    }
    #pragma unroll
    for (int off = 32; off; off >>= 1)
        #pragma unroll
        for (int e = 0; e < 8; ++e) acc[e] += __shfl_down(acc[e], off);
    if (lane == 0) {
        float mx = acc[0];
        #pragma unroll
        for (int e = 1; e < 8; ++e) mx = fmaxf(mx, acc[e]);
        float p[8], sum = 0.0f;
        #pragma unroll
        for (int e = 0; e < 8; ++e) { p[e] = __expf(acc[e] - mx); sum += p[e]; }
        const float inv = 1.0f / sum;
        #pragma unroll
        for (int e = 0; e < 8; ++e) r[(size_t)tok * 8 + e] = p[e] * inv;
    }
}

// ---------------- launch ----------------
extern "C" void kernel_launch(void* const* d_in, const int* in_sizes, int n_in,
                              void* d_out, int out_size, void* d_ws, size_t ws_size,
                              hipStream_t stream) {
    const float* x    = (const float*)d_in[0];
    const float* ln1s = (const float*)d_in[1];
    const float* ln1b = (const float*)d_in[2];
    const float* Wqkv = (const float*)d_in[3];
    const float* bqkv = (const float*)d_in[4];
    const float* Wo   = (const float*)d_in[5];
    const float* bo   = (const float*)d_in[6];
    const float* ln2s = (const float*)d_in[7];
    const float* ln2b = (const float*)d_in[8];
    const float* rW   = (const float*)d_in[9];
    const float* We   = (const float*)d_in[10];
    const float* be   = (const float*)d_in[11];
    const float* Wmo  = (const float*)d_in[12];
    const float* bmo  = (const float*)d_in[13];
    float* out = (float*)d_out;

    char* w = (char*)d_ws;
    auto carve = [&](size_t bytes) {
        void* p = (void*)w;
        w += (bytes + 255) & ~(size_t)255;
        return p;
    };
    const size_t PL = (size_t)T_TOK * DM;  // 4M elements per plane
    u16* qh = (u16*)carve(PL * 2); u16* ql = (u16*)carve(PL * 2);
    u16* kh = (u16*)carve(PL * 2); u16* kl = (u16*)carve(PL * 2);
    u16* vh = (u16*)carve(PL * 2); u16* vl = (u16*)carve(PL * 2);
    u16* ob_h = (u16*)carve(PL * 2); u16* ob_l = (u16*)carve(PL * 2);
    float* x1  = (float*)carve(PL * 4);
    u16* y_h  = (u16*)carve(PL * 2); u16* y_l  = (u16*)carve(PL * 2);
    float* r  = (float*)carve((size_t)T_TOK * 8 * 4);
    u16* Wqkv_h = (u16*)carve((size_t)DM * NQKV * 2);
    u16* Wqkv_l = (u16*)carve((size_t)DM * NQKV * 2);
    u16* Wo_h   = (u16*)carve((size_t)DM * DM * 2);
    u16* Wo_l   = (u16*)carve((size_t)DM * DM * 2);
    u16* We_h   = (u16*)carve((size_t)8 * DM * DM * 2);
    u16* We_l   = (u16*)carve((size_t)8 * DM * DM * 2);
    u16* Wmo_h  = (u16*)carve((size_t)DM * DM * 2);
    u16* Wmo_l  = (u16*)carve((size_t)DM * DM * 2);
    // eo aliases the 8 dead q/k/v/ob planes (exactly 64 MiB)
    u16* eo = qh;
    // comb planes alias dead y planes
    u16* cb_h = y_h;
    u16* cb_l = y_l;

    // ---- weight transpose+split ----
    convert_w<<<dim3(NQKV / 64, DM / 64, 1), 256, 0, stream>>>(Wqkv, Wqkv_h, Wqkv_l, DM, NQKV);
    convert_w<<<dim3(DM / 64, DM / 64, 1), 256, 0, stream>>>(Wo, Wo_h, Wo_l, DM, DM);
    convert_w<<<dim3(DM / 64, DM / 64, 8), 256, 0, stream>>>(We, We_h, We_l, DM, DM);
    convert_w<<<dim3(DM / 64, DM / 64, 1), 256, 0, stream>>>(Wmo, Wmo_h, Wmo_l, DM, DM);

    // 1. y = LN1(x) -> planes
    ln_kernel<<<T_TOK, 256, 0, stream>>>(x, ln1s, ln1b, y_h, y_l);
    // 2. q/k/v planes = split(y @ Wqkv + bqkv) in [b,h,s,d]
    qkv_gemm<<<dim3(NQKV / 128, T_TOK / 128), 256, 0, stream>>>(
        y_h, y_l, Wqkv_h, Wqkv_l, bqkv, qh, ql, kh, kl, vh, vl);
    // 3. ob = attention(q,k,v) -> planes
    attn_kernel<<<dim3(32, 32), 256, 0, stream>>>(qh, ql, kh, kl, vh, vl, ob_h, ob_l);
    // 4. x1 = x + ob @ Wo + bo
    gemm_mfma<0><<<dim3(DM / 128, T_TOK / 128), 256, 0, stream>>>(
        ob_h, ob_l, Wo_h, Wo_l, bo, x, x1, nullptr, DM);
    // 5. y = LN2(x1) -> planes
    ln_kernel<<<T_TOK, 256, 0, stream>>>(x1, ln2s, ln2b, y_h, y_l);
    // 6. r = softmax(y @ rW)
    router_kernel<<<T_TOK, 64, 0, stream>>>(y_h, y_l, rW, r);
    // 7. eo = bf16(y @ We_all + be)  [4096 x 8192]
    gemm_mfma<1><<<dim3(8192 / 128, T_TOK / 128), 256, 0, stream>>>(
        y_h, y_l, We_h, We_l, be, nullptr, nullptr, eo, 8192);
    // 8. comb = sum_e r_e * eo_e -> planes (alias y)
    combine_kernel<<<T_TOK, 256, 0, stream>>>(eo, r, cb_h, cb_l);
    // 9. out = x1 + comb @ Wmo + bmo
    gemm_mfma<0><<<dim3(DM / 128, T_TOK / 128), 256, 0, stream>>>(
        cb_h, cb_l, Wmo_h, Wmo_l, bmo, x1, out, nullptr, DM);
}